// Round 7
// baseline (750.619 us; speedup 1.0000x reference)
//
#include <hip/hip_runtime.h>

// ---------------------------------------------------------------------------
// Cosine-similarity MHA, round 7:
//  - wprep: pre-split At/Ac/Bc/R_w into hi/lo bf16 planes in d_ws (L2-hot);
//    kills all W split8 VALU in attn-P1 and rproj4.
//  - attn P1: wave owns m-tile; X split once into regs, 2 col-tiles inner.
//  - rproj4 reads pre-split R planes.
// b=1024, n_t=50, n_c=200, EMB=128, 8 heads x 32. Block=(batch,head), 512 thr.
// ws layout: [0,393216) proj hi/lo shorts; [393216,524288) R hi/lo shorts;
//            [524288, +52.4MB) cat rows [b][r][h*32+c] f32.
// ---------------------------------------------------------------------------

#define NT 50
#define NC 200
#define EMB 128
#define DH 32
#define NH 8
#define THREADS 512

#define WS_PROJ_LO 98304u       // short offset of proj lo plane
#define WS_R_HI    196608u      // short offset of R hi plane
#define WS_R_LO    229376u      // short offset of R lo plane
#define WS_CAT_B   524288u      // byte offset of cat buffer

typedef __attribute__((ext_vector_type(4))) float f4acc;
typedef __attribute__((ext_vector_type(8))) short bh8;

__device__ __forceinline__ f4acc mfma_bf16(bh8 a, bh8 b, f4acc c) {
    return __builtin_amdgcn_mfma_f32_16x16x32_bf16(a, b, c, 0, 0, 0);
}

__device__ __forceinline__ unsigned short bf16rne(float x) {
    unsigned int u = __float_as_uint(x);
    u += 0x7FFFu + ((u >> 16) & 1u);
    return (unsigned short)(u >> 16);
}

// 8 consecutive f32 -> packed hi/lo bf16 fragments.
// hi = RNE(x) via v_cvt_pk_bf16_f32, lo = RNE(x - (float)hi). Pair order is
// applied identically to A and B fragments -> MFMA dots invariant.
__device__ __forceinline__ void split8(const float* __restrict__ p, bh8& hi, bh8& lo) {
    float4 x0 = *reinterpret_cast<const float4*>(p);
    float4 x1 = *reinterpret_cast<const float4*>(p + 4);
    float xs[8] = {x0.x, x0.y, x0.z, x0.w, x1.x, x1.y, x1.z, x1.w};
    union { unsigned int w[4]; bh8 v; } H, L;
    #pragma unroll
    for (int i = 0; i < 4; ++i) {
        const float a = xs[2 * i], b = xs[2 * i + 1];
        unsigned int hw, lw;
        asm("v_cvt_pk_bf16_f32 %0, %1, %2" : "=v"(hw) : "v"(a), "v"(b));
        const float ha = __uint_as_float(hw << 16);
        const float hb = __uint_as_float(hw & 0xFFFF0000u);
        const float la = a - ha, lb = b - hb;
        asm("v_cvt_pk_bf16_f32 %0, %1, %2" : "=v"(lw) : "v"(la), "v"(lb));
        H.w[i] = hw; L.w[i] = lw;
    }
    hi = H.v; lo = L.v;
}

// ---- wprep: split all weights into hi/lo bf16 planes in ws ----
__global__ __launch_bounds__(512) void wprep(
    const float* __restrict__ At_w, const float* __restrict__ Ac_w,
    const float* __restrict__ Bc_w, const float* __restrict__ R_w,
    unsigned short* __restrict__ ws)
{
    const int u = blockIdx.x * 512 + threadIdx.x;     // 16384 units of 8 elems
    bh8 h8, l8;
    if (u < 12288) {                                  // proj: [3][256][128]
        const int p = u >> 12, rem = u & 4095;
        const int col = rem >> 4, e0 = (rem & 15) << 3;
        const float* W = (p == 0) ? At_w : (p == 1) ? Ac_w : Bc_w;
        split8(W + (size_t)col * 128 + e0, h8, l8);
        const size_t o = ((size_t)p * 256 + col) * 128 + e0;
        *reinterpret_cast<bh8*>(ws + o) = h8;
        *reinterpret_cast<bh8*>(ws + WS_PROJ_LO + o) = l8;
    } else {                                          // R: [128][256]
        const int u2 = u - 12288;
        const int e = u2 >> 5, k0 = (u2 & 31) << 3;
        split8(R_w + (size_t)e * 256 + k0, h8, l8);
        const size_t o = (size_t)e * 256 + k0;
        *reinterpret_cast<bh8*>(ws + WS_R_HI + o) = h8;
        *reinterpret_cast<bh8*>(ws + WS_R_LO + o) = l8;
    }
}

// LDS layout (byte offsets into smem[39872]):
//   sVT 0      : 32 x 232 shorts = 14848   v^T [col][k]
//   sK  14848  : 200 x 40 shorts = 16000
//   sQ  30848  : 64 x 40 shorts  = 5120    (ends 35968)
//   sP  14848  : 50 x 232 shorts = 23200   (aliases sK+sQ, ends 38048)
//   spb 38048  : 200 f32
//   sM  38848  : 128 f32 (per-half row max)
//   sSm 39360  : 128 f32 (per-half row sum)

template <int WSP>
__global__ __launch_bounds__(THREADS, 4) void attn_mfma(
    const float* __restrict__ gq, const float* __restrict__ gk,
    const float* __restrict__ gv,
    const float* __restrict__ At_w, const float* __restrict__ At_b,
    const float* __restrict__ Ac_w, const float* __restrict__ Ac_b,
    const float* __restrict__ Bc_w, const float* __restrict__ Bc_b,
    const float* __restrict__ pos_bias,
    const float* __restrict__ R_w, const float* __restrict__ R_b,
    float* __restrict__ out, float* __restrict__ att,
    float* __restrict__ cat, const unsigned short* __restrict__ wsp,
    int nbat)
{
    const int t = threadIdx.x;
    const int p = blockIdx.x;
    const int chunk = (nbat * NH) >> 3;
    const int lj = (p & 7) * chunk + (p >> 3);   // XCD-chunk swizzle (bijective)
    const int b = lj >> 3;
    const int h = lj & 7;
    const int lane = t & 63, wave = t >> 6;
    const int l15 = lane & 15, g = lane >> 4;

    __shared__ __align__(16) unsigned char smem[39872];
    unsigned short* sVT = reinterpret_cast<unsigned short*>(smem);
    unsigned short* sK  = reinterpret_cast<unsigned short*>(smem + 14848);
    unsigned short* sQ  = reinterpret_cast<unsigned short*>(smem + 30848);
    unsigned short* sP  = reinterpret_cast<unsigned short*>(smem + 14848);
    float* spb = reinterpret_cast<float*>(smem + 38048);
    float* sM  = reinterpret_cast<float*>(smem + 38848);
    float* sSm = reinterpret_cast<float*>(smem + 39360);

    // ---- P0: zero sVT K-pad (k=200..227 for 32 cols), stage pos_bias ----
    if (t < 448) {
        unsigned int* v32 = reinterpret_cast<unsigned int*>(sVT);
        const int col = t / 14, i = t - col * 14;
        v32[col * 116 + 100 + i] = 0u;
    }
    if (t < NC) spb[t] = pos_bias[t];

    // ---- P1: projections ----
    if (WSP) {
        // presplit-W path: wave owns m-tiles; X split once, 2 col-tiles inner
        const int s0 = (wave * 30) >> 3;
        const int s1 = ((wave + 1) * 30) >> 3;
        for (int id = s0; id < s1; ++id) {
            int pidx, mt2;
            if (id < 4)       { pidx = 0; mt2 = id; }
            else if (id < 17) { pidx = 1; mt2 = id - 4; }
            else              { pidx = 2; mt2 = id - 17; }
            const int nrows = pidx ? NC : NT;
            const float* Xb = (pidx == 0) ? gq : (pidx == 1) ? gk : gv;
            const float* Wb = (pidx == 0) ? At_b : (pidx == 1) ? Ac_b : Bc_b;
            int ar = mt2 * 16 + l15; if (ar > nrows - 1) ar = nrows - 1;
            const float* ap = Xb + (size_t)b * nrows * EMB + (size_t)ar * EMB + (g << 3);
            bh8 xh[4], xl[4];
            #pragma unroll
            for (int ks = 0; ks < 4; ++ks) split8(ap + ks * 32, xh[ks], xl[ks]);
            #pragma unroll
            for (int nt2 = 0; nt2 < 2; ++nt2) {
                const int lc = nt2 * 16 + l15;        // local col in head
                const int gcol = h * DH + lc;         // global col in 256
                const unsigned short* whp =
                    wsp + ((size_t)pidx * 256 + gcol) * 128 + (g << 3);
                const unsigned short* wlp = whp + WS_PROJ_LO;
                const float bias = Wb[gcol];
                f4acc a2 = {bias, bias, bias, bias};
                #pragma unroll
                for (int ks = 0; ks < 4; ++ks) {
                    const bh8 wh = *reinterpret_cast<const bh8*>(whp + ks * 32);
                    const bh8 wl = *reinterpret_cast<const bh8*>(wlp + ks * 32);
                    a2 = mfma_bf16(xh[ks], wh, a2);
                    a2 = mfma_bf16(xl[ks], wh, a2);
                    a2 = mfma_bf16(xh[ks], wl, a2);
                }
                #pragma unroll
                for (int r = 0; r < 4; ++r) {
                    const int row = mt2 * 16 + (g << 2) + r;
                    if (row < nrows) {
                        const unsigned short hv = bf16rne(a2[r]);
                        if (pidx == 0)      sQ[row * 40 + lc] = hv;
                        else if (pidx == 1) sK[row * 40 + lc] = hv;
                        else                sVT[lc * 232 + row] = hv;
                    }
                }
            }
        }
    } else {
        // self-contained fallback (splits W on the fly, strip-hoisted)
        const int s0 = (wave * 60) >> 3;
        const int s1 = ((wave + 1) * 60) >> 3;
        int cp = -1, cn = -1;
        bh8 wh[4], wl[4];
        float bias = 0.f;
        for (int id = s0; id < s1; ++id) {
            int pidx, nt, mt2;
            if (id < 8)       { pidx = 0; nt = id >> 2; mt2 = id & 3; }
            else if (id < 34) { int j = id - 8;  pidx = 1; nt = j / 13; mt2 = j - nt * 13; }
            else              { int j = id - 34; pidx = 2; nt = j / 13; mt2 = j - nt * 13; }
            const int col = (nt << 4) + l15;
            if (pidx != cp || nt != cn) {
                cp = pidx; cn = nt;
                const float* Wm = (pidx == 0) ? At_w : (pidx == 1) ? Ac_w : Bc_w;
                const float* Wbp = (pidx == 0) ? At_b : (pidx == 1) ? Ac_b : Bc_b;
                const float* bp = Wm + (size_t)(h * DH + col) * EMB + (g << 3);
                #pragma unroll
                for (int ks = 0; ks < 4; ++ks) split8(bp + ks * 32, wh[ks], wl[ks]);
                bias = Wbp[h * DH + col];
            }
            const int nrows = (pidx == 0) ? NT : NC;
            const float* Xb = (pidx == 0) ? gq : (pidx == 1) ? gk : gv;
            int ar = mt2 * 16 + l15; if (ar > nrows - 1) ar = nrows - 1;
            const float* ap = Xb + (size_t)b * nrows * EMB + (size_t)ar * EMB + (g << 3);
            f4acc acc2 = {bias, bias, bias, bias};
            #pragma unroll
            for (int ks = 0; ks < 4; ++ks) {
                bh8 xh, xl;
                split8(ap + ks * 32, xh, xl);
                acc2 = mfma_bf16(xh, wh[ks], acc2);
                acc2 = mfma_bf16(xl, wh[ks], acc2);
                acc2 = mfma_bf16(xh, wl[ks], acc2);
            }
            #pragma unroll
            for (int r = 0; r < 4; ++r) {
                const int row = mt2 * 16 + (g << 2) + r;
                if (row < nrows) {
                    const unsigned short hv = bf16rne(acc2[r]);
                    if (pidx == 0)      sQ[row * 40 + col] = hv;
                    else if (pidx == 1) sK[row * 40 + col] = hv;
                    else                sVT[col * 232 + row] = hv;
                }
            }
        }
    }
    __syncthreads();

    // ---- P3: scores in registers; norms in-register from the fragments ----
    const int mt = wave & 3, hf = wave >> 2;
    const int m0 = mt << 4;
    const int row64 = m0 + (g << 2);
    int arow = m0 + l15; if (arow > NT - 1) arow = NT - 1;
    const bh8 aq = *reinterpret_cast<const bh8*>(sQ + arow * 40 + (g << 3));

    // qn: A-frag row m0+l15 lives on the 4 lanes {l15, l15+16, +32, +48}
    float qn2 = 0.f;
    #pragma unroll
    for (int e = 0; e < 8; ++e) {
        const float v = __uint_as_float(((unsigned int)(unsigned short)aq[e]) << 16);
        qn2 += v * v;
    }
    qn2 += __shfl_xor(qn2, 16);
    qn2 += __shfl_xor(qn2, 32);
    float qn_r[4];                       // move qn to this lane's 4 C-rows
    #pragma unroll
    for (int r = 0; r < 4; ++r) qn_r[r] = sqrtf(__shfl(qn2, (g << 2) + r, 64));

    f4acc acc[7];
    #pragma unroll
    for (int i = 0; i < 7; ++i) {
        const int nt = hf * 7 + i;
        if (nt < 13) {
            const int col = (nt << 4) + l15;
            const int bc = (col < NC) ? col : (NC - 1);
            const bh8 bk = *reinterpret_cast<const bh8*>(sK + bc * 40 + (g << 3));
            float kn2 = 0.f;
            #pragma unroll
            for (int e = 0; e < 8; ++e) {
                const float v = __uint_as_float(((unsigned int)(unsigned short)bk[e]) << 16);
                kn2 += v * v;
            }
            kn2 += __shfl_xor(kn2, 16);  // kn lands on C-col lanes directly
            kn2 += __shfl_xor(kn2, 32);
            const float kn = sqrtf(kn2);
            f4acc c = {0.f, 0.f, 0.f, 0.f};
            c = mfma_bf16(aq, bk, c);
            const float pb = spb[bc];
            #pragma unroll
            for (int r = 0; r < 4; ++r)
                acc[i][r] = (col < NC) ? c[r] / fmaxf(qn_r[r] * kn, 1e-6f) + pb
                                       : -1e30f;
        }
    }
    __syncthreads();                 // sK/sQ dead; sP region live from here

    // ---- P4a: sP K-pad zero (ALL 50 rows; grid-stride) + per-half row max ----
    {
        unsigned int* p32 = reinterpret_cast<unsigned int*>(sP);
        for (int tt = t; tt < 700; tt += THREADS) {
            const int row = tt / 14, i = tt - row * 14;
            p32[row * 116 + 100 + i] = 0u;
        }
    }
    {
        float mloc[4] = {-1e30f, -1e30f, -1e30f, -1e30f};
        #pragma unroll
        for (int i = 0; i < 7; ++i) {
            if (hf * 7 + i < 13) {
                #pragma unroll
                for (int r = 0; r < 4; ++r) mloc[r] = fmaxf(mloc[r], acc[i][r]);
            }
        }
        #pragma unroll
        for (int r = 0; r < 4; ++r) {
            mloc[r] = fmaxf(mloc[r], __shfl_xor(mloc[r], 1));
            mloc[r] = fmaxf(mloc[r], __shfl_xor(mloc[r], 2));
            mloc[r] = fmaxf(mloc[r], __shfl_xor(mloc[r], 4));
            mloc[r] = fmaxf(mloc[r], __shfl_xor(mloc[r], 8));
        }
        if (l15 == 0) {
            #pragma unroll
            for (int r = 0; r < 4; ++r) sM[hf * 64 + row64 + r] = mloc[r];
        }
    }
    __syncthreads();

    // ---- P4b: global max, exp, per-half sums ----
    {
        float mx[4], sl[4] = {0.f, 0.f, 0.f, 0.f};
        #pragma unroll
        for (int r = 0; r < 4; ++r)
            mx[r] = fmaxf(sM[row64 + r], sM[64 + row64 + r]);
        #pragma unroll
        for (int i = 0; i < 7; ++i) {
            if (hf * 7 + i < 13) {
                #pragma unroll
                for (int r = 0; r < 4; ++r) {
                    float e = __expf(acc[i][r] - mx[r]);
                    acc[i][r] = e;
                    sl[r] += e;
                }
            }
        }
        #pragma unroll
        for (int r = 0; r < 4; ++r) {
            sl[r] += __shfl_xor(sl[r], 1);
            sl[r] += __shfl_xor(sl[r], 2);
            sl[r] += __shfl_xor(sl[r], 4);
            sl[r] += __shfl_xor(sl[r], 8);
        }
        if (l15 == 0) {
            #pragma unroll
            for (int r = 0; r < 4; ++r) sSm[hf * 64 + row64 + r] = sl[r];
        }
    }
    __syncthreads();

    // ---- P4c: normalize, write att (f32 global) + P (bf16 LDS) ----
    {
        float inv[4];
        #pragma unroll
        for (int r = 0; r < 4; ++r)
            inv[r] = 1.0f / (sSm[row64 + r] + sSm[64 + row64 + r]);
        float* attb = att + (size_t)(b * NH + h) * NT * NC;
        #pragma unroll
        for (int i = 0; i < 7; ++i) {
            const int nt = hf * 7 + i;
            if (nt < 13) {
                const int col = (nt << 4) + l15;
                if (col < NC) {
                    #pragma unroll
                    for (int r = 0; r < 4; ++r) {
                        const int row = row64 + r;
                        if (row < NT) {
                            const float v = acc[i][r] * inv[r];
                            attb[row * NC + col] = v;
                            sP[row * 232 + col] = bf16rne(v);
                        }
                    }
                }
            }
        }
    }
    __syncthreads();

    // ---- P5: PV (bf16 MFMA, K=224 zero-padded) ----
    {
        const int pnt = wave >> 2;               // 2 col-tiles of 16 (DH=32)
        const unsigned short* pA = sP + arow * 232;
        const unsigned short* pB = sVT + (size_t)((pnt << 4) + l15) * 232;
        f4acc o = {0.f, 0.f, 0.f, 0.f};
        #pragma unroll
        for (int ks = 0; ks < 7; ++ks) {
            const bh8 a = *reinterpret_cast<const bh8*>(pA + ks * 32 + (g << 3));
            const bh8 v = *reinterpret_cast<const bh8*>(pB + ks * 32 + (g << 3));
            o = mfma_bf16(a, v, o);
        }
        if (WSP) {
            // cat layout: [b][row][h*32 + c]
            float* wsb = cat + (size_t)b * (NT * NH * DH) + h * DH;
            #pragma unroll
            for (int r = 0; r < 4; ++r) {
                const int row = row64 + r;
                if (row < NT) wsb[(size_t)row * (NH * DH) + (pnt << 4) + l15] = o[r];
            }
        } else {
            __syncthreads();
            float* sOH = reinterpret_cast<float*>(smem);   // 6400 B over sVT
            #pragma unroll
            for (int r = 0; r < 4; ++r) {
                const int row = row64 + r;
                if (row < NT) sOH[row * DH + (pnt << 4) + l15] = o[r];
            }
            __syncthreads();
            for (int oo = t; oo < NT * EMB; oo += THREADS) {
                const int r = oo >> 7, e = oo & 127;
                float s = (h == 0) ? R_b[e] : 0.f;
                const float* rw = R_w + (size_t)e * (NH * DH) + h * DH;
                const float* oh = sOH + r * DH;
                #pragma unroll
                for (int c = 0; c < DH; ++c) s += oh[c] * rw[c];
                atomicAdd(&out[((size_t)b * NT + r) * EMB + e], s);
            }
        }
    }
}

// rproj4: MFMA GEMM. out[51200x128] = cat[51200x256] @ R_w[128x256]^T + R_b.
// B fragments from pre-split R planes (L2-hot); A split on the fly.
__global__ __launch_bounds__(256, 4) void rproj4(
    const float* __restrict__ cat, const unsigned short* __restrict__ rhi,
    const float* __restrict__ R_b, float* __restrict__ out)
{
    const int t = threadIdx.x;
    const int lane = t & 63, wave = t >> 6;
    const int l15 = lane & 15, g = lane >> 4;
    const int m0 = blockIdx.x * 64 + wave * 16;
    const float* ap = cat + (size_t)(m0 + l15) * 256 + (g << 3);
    const unsigned short* rlo = rhi + (WS_R_LO - WS_R_HI);

    f4acc acc[8];
    #pragma unroll
    for (int nt = 0; nt < 8; ++nt) {
        const float rb = R_b[nt * 16 + l15];
        acc[nt][0] = rb; acc[nt][1] = rb; acc[nt][2] = rb; acc[nt][3] = rb;
    }
    #pragma unroll
    for (int ks = 0; ks < 8; ++ks) {
        bh8 ah, al;
        split8(ap + ks * 32, ah, al);
        #pragma unroll
        for (int nt = 0; nt < 8; ++nt) {
            const size_t o = (size_t)(nt * 16 + l15) * 256 + ks * 32 + (g << 3);
            const bh8 bh_ = *reinterpret_cast<const bh8*>(rhi + o);
            const bh8 bl_ = *reinterpret_cast<const bh8*>(rlo + o);
            acc[nt] = mfma_bf16(ah, bh_, acc[nt]);
            acc[nt] = mfma_bf16(al, bh_, acc[nt]);
            acc[nt] = mfma_bf16(ah, bl_, acc[nt]);
        }
    }
    const int row = m0 + (g << 2);
    #pragma unroll
    for (int nt = 0; nt < 8; ++nt) {
        #pragma unroll
        for (int r = 0; r < 4; ++r)
            out[(size_t)(row + r) * EMB + nt * 16 + l15] = acc[nt][r];
    }
}

extern "C" void kernel_launch(void* const* d_in, const int* in_sizes, int n_in,
                              void* d_out, int out_size, void* d_ws, size_t ws_size,
                              hipStream_t stream)
{
    const float* gq   = (const float*)d_in[0];
    const float* gk   = (const float*)d_in[1];
    const float* gv   = (const float*)d_in[2];
    const float* At_w = (const float*)d_in[3];
    const float* At_b = (const float*)d_in[4];
    const float* Ac_w = (const float*)d_in[5];
    const float* Ac_b = (const float*)d_in[6];
    const float* Bc_w = (const float*)d_in[7];
    const float* Bc_b = (const float*)d_in[8];
    const float* pb   = (const float*)d_in[9];
    const float* R_w  = (const float*)d_in[10];
    const float* R_b  = (const float*)d_in[11];

    const int nbat = in_sizes[0] / (NT * EMB);   // 1024
    float* out = (float*)d_out;
    float* att = out + (size_t)nbat * NT * EMB;

    const size_t ws_need = WS_CAT_B + (size_t)nbat * NT * NH * DH * sizeof(float);
    const int nwg = nbat * NH;

    if (ws_size >= ws_need) {
        unsigned short* wsp = (unsigned short*)d_ws;
        float* cat = (float*)((char*)d_ws + WS_CAT_B);
        wprep<<<32, 512, 0, stream>>>(At_w, Ac_w, Bc_w, R_w, wsp);
        attn_mfma<1><<<nwg, THREADS, 0, stream>>>(
            gq, gk, gv, At_w, At_b, Ac_w, Ac_b, Bc_w, Bc_b, pb, R_w, R_b,
            out, att, cat, wsp, nbat);
        rproj4<<<(nbat * NT) / 64, 256, 0, stream>>>(cat, wsp + WS_R_HI, R_b, out);
    } else {
        hipMemsetAsync(d_out, 0, (size_t)nbat * NT * EMB * sizeof(float), stream);
        attn_mfma<0><<<nwg, THREADS, 0, stream>>>(
            gq, gk, gv, At_w, At_b, Ac_w, Ac_b, Bc_w, Bc_b, pb, R_w, R_b,
            out, att, nullptr, nullptr, nbat);
    }
}

// Round 8
// 664.541 us; speedup vs baseline: 1.1295x; 1.1295x over previous
//
#include <hip/hip_runtime.h>

// ---------------------------------------------------------------------------
// Cosine-similarity MHA, round 8:
//  - P1: strip-hoisted W (register reuse, round-6) FROM presplit planes
//    (round-7) -> no W split8 VALU, no per-tile W load latency.
//  - Q/K rows pre-normalized in LDS -> P3 is 1 MFMA + 4 FMA per tile.
//  - No-max softmax: |cos + pb| <= 1.003 bounds exp; log2e folded -> 1 v_exp.
// b=1024, n_t=50, n_c=200, EMB=128, 8 heads x 32. Block=(batch,head), 512 thr.
// ws: [0,393216) proj hi/lo shorts; [393216,524288) R hi/lo shorts;
//     [524288,+52.4MB) cat rows [b][r][h*32+c] f32.
// ---------------------------------------------------------------------------

#define NT 50
#define NC 200
#define EMB 128
#define DH 32
#define NH 8
#define THREADS 512
#define LOG2E 1.44269504088896340736f

#define WS_PROJ_LO 98304u       // short offset of proj lo plane
#define WS_R_HI    196608u      // short offset of R hi plane
#define WS_R_LO    229376u      // short offset of R lo plane
#define WS_CAT_B   524288u      // byte offset of cat buffer

typedef __attribute__((ext_vector_type(4))) float f4acc;
typedef __attribute__((ext_vector_type(8))) short bh8;

__device__ __forceinline__ f4acc mfma_bf16(bh8 a, bh8 b, f4acc c) {
    return __builtin_amdgcn_mfma_f32_16x16x32_bf16(a, b, c, 0, 0, 0);
}

__device__ __forceinline__ unsigned short bf16rne(float x) {
    unsigned int u = __float_as_uint(x);
    u += 0x7FFFu + ((u >> 16) & 1u);
    return (unsigned short)(u >> 16);
}

// 8 consecutive f32 -> packed hi/lo bf16 fragments (RNE via v_cvt_pk_bf16_f32;
// pair order applied identically to A and B fragments -> MFMA dots invariant).
__device__ __forceinline__ void split8(const float* __restrict__ p, bh8& hi, bh8& lo) {
    float4 x0 = *reinterpret_cast<const float4*>(p);
    float4 x1 = *reinterpret_cast<const float4*>(p + 4);
    float xs[8] = {x0.x, x0.y, x0.z, x0.w, x1.x, x1.y, x1.z, x1.w};
    union { unsigned int w[4]; bh8 v; } H, L;
    #pragma unroll
    for (int i = 0; i < 4; ++i) {
        const float a = xs[2 * i], b = xs[2 * i + 1];
        unsigned int hw, lw;
        asm("v_cvt_pk_bf16_f32 %0, %1, %2" : "=v"(hw) : "v"(a), "v"(b));
        const float ha = __uint_as_float(hw << 16);
        const float hb = __uint_as_float(hw & 0xFFFF0000u);
        const float la = a - ha, lb = b - hb;
        asm("v_cvt_pk_bf16_f32 %0, %1, %2" : "=v"(lw) : "v"(la), "v"(lb));
        H.w[i] = hw; L.w[i] = lw;
    }
    hi = H.v; lo = L.v;
}

// ---- wprep: split all weights into hi/lo bf16 planes in ws ----
__global__ __launch_bounds__(512) void wprep(
    const float* __restrict__ At_w, const float* __restrict__ Ac_w,
    const float* __restrict__ Bc_w, const float* __restrict__ R_w,
    unsigned short* __restrict__ ws)
{
    const int u = blockIdx.x * 512 + threadIdx.x;     // 16384 units of 8 elems
    bh8 h8, l8;
    if (u < 12288) {                                  // proj: [3][256][128]
        const int p = u >> 12, rem = u & 4095;
        const int col = rem >> 4, e0 = (rem & 15) << 3;
        const float* W = (p == 0) ? At_w : (p == 1) ? Ac_w : Bc_w;
        split8(W + (size_t)col * 128 + e0, h8, l8);
        const size_t o = ((size_t)p * 256 + col) * 128 + e0;
        *reinterpret_cast<bh8*>(ws + o) = h8;
        *reinterpret_cast<bh8*>(ws + WS_PROJ_LO + o) = l8;
    } else {                                          // R: [128][256]
        const int u2 = u - 12288;
        const int e = u2 >> 5, k0 = (u2 & 31) << 3;
        split8(R_w + (size_t)e * 256 + k0, h8, l8);
        const size_t o = (size_t)e * 256 + k0;
        *reinterpret_cast<bh8*>(ws + WS_R_HI + o) = h8;
        *reinterpret_cast<bh8*>(ws + WS_R_LO + o) = l8;
    }
}

// LDS layout (byte offsets into smem[39872]):
//   sVT 0      : 32 x 232 shorts = 14848   v^T [col][k]  (NOT normalized)
//   sK  14848  : 200 x 40 shorts = 16000   k-hat rows
//   sQ  30848  : 64 x 40 shorts  = 5120    q-hat rows (ends 35968)
//   sP  14848  : 50 x 232 shorts = 23200   (aliases sK+sQ, ends 38048)
//   spb 38048  : 200 f32  (pos_bias * LOG2E)
//   sSm 39360  : 128 f32  (per-half row sum)

template <int WSP>
__global__ __launch_bounds__(THREADS, 4) void attn_mfma(
    const float* __restrict__ gq, const float* __restrict__ gk,
    const float* __restrict__ gv,
    const float* __restrict__ At_w, const float* __restrict__ At_b,
    const float* __restrict__ Ac_w, const float* __restrict__ Ac_b,
    const float* __restrict__ Bc_w, const float* __restrict__ Bc_b,
    const float* __restrict__ pos_bias,
    const float* __restrict__ R_w, const float* __restrict__ R_b,
    float* __restrict__ out, float* __restrict__ att,
    float* __restrict__ cat, const unsigned short* __restrict__ wsp,
    int nbat)
{
    const int t = threadIdx.x;
    const int p = blockIdx.x;
    const int chunk = (nbat * NH) >> 3;
    const int lj = (p & 7) * chunk + (p >> 3);   // XCD-chunk swizzle (bijective)
    const int b = lj >> 3;
    const int h = lj & 7;
    const int lane = t & 63, wave = t >> 6;
    const int l15 = lane & 15, g = lane >> 4;

    __shared__ __align__(16) unsigned char smem[39872];
    unsigned short* sVT = reinterpret_cast<unsigned short*>(smem);
    unsigned short* sK  = reinterpret_cast<unsigned short*>(smem + 14848);
    unsigned short* sQ  = reinterpret_cast<unsigned short*>(smem + 30848);
    unsigned short* sP  = reinterpret_cast<unsigned short*>(smem + 14848);
    float* spb = reinterpret_cast<float*>(smem + 38048);
    float* sSm = reinterpret_cast<float*>(smem + 39360);

    // ---- P0: zero sVT K-pad (k=200..227 for 32 cols), stage pos_bias*log2e ----
    if (t < 448) {
        unsigned int* v32 = reinterpret_cast<unsigned int*>(sVT);
        const int col = t / 14, i = t - col * 14;
        v32[col * 116 + 100 + i] = 0u;
    }
    if (t < NC) spb[t] = pos_bias[t] * LOG2E;

    // ---- P1: projections, strip-hoisted W ----
    {
        const int s0 = (wave * 60) >> 3;
        const int s1 = ((wave + 1) * 60) >> 3;
        int cp = -1, cn = -1;
        bh8 wh[4], wl[4];
        float bias = 0.f;
        for (int id = s0; id < s1; ++id) {
            int pidx, nt, mt2;
            if (id < 8)       { pidx = 0; nt = id >> 2; mt2 = id & 3; }
            else if (id < 34) { int j = id - 8;  pidx = 1; nt = j / 13; mt2 = j - nt * 13; }
            else              { int j = id - 34; pidx = 2; nt = j / 13; mt2 = j - nt * 13; }
            const int col = (nt << 4) + l15;          // 0..31 within head
            if (pidx != cp || nt != cn) {
                cp = pidx; cn = nt;
                const int gcol = h * DH + col;        // 0..255
                if (WSP) {
                    const unsigned short* whp =
                        wsp + ((size_t)pidx * 256 + gcol) * 128 + (g << 3);
                    const unsigned short* wlp = whp + WS_PROJ_LO;
                    #pragma unroll
                    for (int ks = 0; ks < 4; ++ks) {
                        wh[ks] = *reinterpret_cast<const bh8*>(whp + ks * 32);
                        wl[ks] = *reinterpret_cast<const bh8*>(wlp + ks * 32);
                    }
                } else {
                    const float* Wm = (pidx == 0) ? At_w : (pidx == 1) ? Ac_w : Bc_w;
                    const float* bp = Wm + (size_t)gcol * EMB + (g << 3);
                    #pragma unroll
                    for (int ks = 0; ks < 4; ++ks) split8(bp + ks * 32, wh[ks], wl[ks]);
                }
                const float* Wb = (pidx == 0) ? At_b : (pidx == 1) ? Ac_b : Bc_b;
                bias = Wb[gcol];
            }
            const int nrows = (pidx == 0) ? NT : NC;
            const float* Xb = (pidx == 0) ? gq : (pidx == 1) ? gk : gv;
            int ar = mt2 * 16 + l15; if (ar > nrows - 1) ar = nrows - 1;
            const float* ap = Xb + (size_t)b * nrows * EMB + (size_t)ar * EMB + (g << 3);
            f4acc acc2 = {bias, bias, bias, bias};
            #pragma unroll
            for (int ks = 0; ks < 4; ++ks) {
                bh8 xh, xl;
                split8(ap + ks * 32, xh, xl);
                acc2 = mfma_bf16(xh, wh[ks], acc2);
                acc2 = mfma_bf16(xl, wh[ks], acc2);
                acc2 = mfma_bf16(xh, wl[ks], acc2);
            }
            #pragma unroll
            for (int r = 0; r < 4; ++r) {
                const int row = mt2 * 16 + (g << 2) + r;
                if (row < nrows) {
                    const unsigned short hv = bf16rne(acc2[r]);
                    if (pidx == 0)      sQ[row * 40 + col] = hv;
                    else if (pidx == 1) sK[row * 40 + col] = hv;
                    else                sVT[col * 232 + row] = hv;
                }
            }
        }
    }
    __syncthreads();

    // ---- P2: normalize K rows (0..199) and Q rows (200..249) in LDS ----
    if (t < 250) {
        unsigned short* rowp = (t < 200) ? (sK + t * 40) : (sQ + (t - 200) * 40);
        unsigned int* w32 = reinterpret_cast<unsigned int*>(rowp);
        unsigned int w[16];
        #pragma unroll
        for (int i = 0; i < 16; ++i) w[i] = w32[i];
        float s = 0.f;
        #pragma unroll
        for (int i = 0; i < 16; ++i) {
            const float a = __uint_as_float(w[i] << 16);
            const float c = __uint_as_float(w[i] & 0xFFFF0000u);
            s += a * a + c * c;
        }
        const float rs = rsqrtf(fmaxf(s, 1e-12f));
        #pragma unroll
        for (int i = 0; i < 16; ++i) {
            const float a = __uint_as_float(w[i] << 16) * rs;
            const float c = __uint_as_float(w[i] & 0xFFFF0000u) * rs;
            unsigned int pw;
            asm("v_cvt_pk_bf16_f32 %0, %1, %2" : "=v"(pw) : "v"(a), "v"(c));
            w32[i] = pw;
        }
    }
    __syncthreads();

    // ---- P3: scores = qhat.khat (1 MFMA + 4 FMA per tile; log2e folded) ----
    const int mt = wave & 3, hf = wave >> 2;
    const int m0 = mt << 4;
    const int row64 = m0 + (g << 2);
    int arow = m0 + l15; if (arow > NT - 1) arow = NT - 1;
    const bh8 aq = *reinterpret_cast<const bh8*>(sQ + arow * 40 + (g << 3));

    f4acc acc[7];
    #pragma unroll
    for (int i = 0; i < 7; ++i) {
        const int nt = hf * 7 + i;
        if (nt < 13) {
            const int col = (nt << 4) + l15;
            const int bc = (col < NC) ? col : (NC - 1);
            const bh8 bk = *reinterpret_cast<const bh8*>(sK + bc * 40 + (g << 3));
            f4acc c = {0.f, 0.f, 0.f, 0.f};
            c = mfma_bf16(aq, bk, c);
            const float pbl = spb[bc];
            #pragma unroll
            for (int r = 0; r < 4; ++r)
                acc[i][r] = (col < NC) ? c[r] * LOG2E + pbl : -1e30f;
        }
    }
    __syncthreads();                 // sK/sQ dead; sP region live from here

    // ---- P4: no-max softmax: exp2 directly (|score*log2e| <= 1.45) ----
    {
        unsigned int* p32 = reinterpret_cast<unsigned int*>(sP);
        for (int tt = t; tt < 700; tt += THREADS) {    // sP K-pad zero
            const int row = tt / 14, i = tt - row * 14;
            p32[row * 116 + 100 + i] = 0u;
        }
    }
    {
        float sl[4] = {0.f, 0.f, 0.f, 0.f};
        #pragma unroll
        for (int i = 0; i < 7; ++i) {
            if (hf * 7 + i < 13) {
                #pragma unroll
                for (int r = 0; r < 4; ++r) {
                    const float e = __builtin_exp2f(acc[i][r]);
                    acc[i][r] = e;
                    sl[r] += e;
                }
            }
        }
        #pragma unroll
        for (int r = 0; r < 4; ++r) {
            sl[r] += __shfl_xor(sl[r], 1);
            sl[r] += __shfl_xor(sl[r], 2);
            sl[r] += __shfl_xor(sl[r], 4);
            sl[r] += __shfl_xor(sl[r], 8);
        }
        if (l15 == 0) {
            #pragma unroll
            for (int r = 0; r < 4; ++r) sSm[hf * 64 + row64 + r] = sl[r];
        }
    }
    __syncthreads();

    // ---- P4c: normalize, write att (f32 global) + P (bf16 LDS) ----
    {
        float inv[4];
        #pragma unroll
        for (int r = 0; r < 4; ++r)
            inv[r] = 1.0f / (sSm[row64 + r] + sSm[64 + row64 + r]);
        float* attb = att + (size_t)(b * NH + h) * NT * NC;
        #pragma unroll
        for (int i = 0; i < 7; ++i) {
            const int nt = hf * 7 + i;
            if (nt < 13) {
                const int col = (nt << 4) + l15;
                if (col < NC) {
                    #pragma unroll
                    for (int r = 0; r < 4; ++r) {
                        const int row = row64 + r;
                        if (row < NT) {
                            const float v = acc[i][r] * inv[r];
                            attb[row * NC + col] = v;
                            sP[row * 232 + col] = bf16rne(v);
                        }
                    }
                }
            }
        }
    }
    __syncthreads();

    // ---- P5: PV (bf16 MFMA, K=224 zero-padded) ----
    {
        const int pnt = wave >> 2;               // 2 col-tiles of 16 (DH=32)
        const unsigned short* pA = sP + arow * 232;
        const unsigned short* pB = sVT + (size_t)((pnt << 4) + l15) * 232;
        f4acc o = {0.f, 0.f, 0.f, 0.f};
        #pragma unroll
        for (int ks = 0; ks < 7; ++ks) {
            const bh8 a = *reinterpret_cast<const bh8*>(pA + ks * 32 + (g << 3));
            const bh8 v = *reinterpret_cast<const bh8*>(pB + ks * 32 + (g << 3));
            o = mfma_bf16(a, v, o);
        }
        if (WSP) {
            // cat layout: [b][row][h*32 + c]
            float* wsb = cat + (size_t)b * (NT * NH * DH) + h * DH;
            #pragma unroll
            for (int r = 0; r < 4; ++r) {
                const int row = row64 + r;
                if (row < NT) wsb[(size_t)row * (NH * DH) + (pnt << 4) + l15] = o[r];
            }
        } else {
            __syncthreads();
            float* sOH = reinterpret_cast<float*>(smem);   // 6400 B over sVT
            #pragma unroll
            for (int r = 0; r < 4; ++r) {
                const int row = row64 + r;
                if (row < NT) sOH[row * DH + (pnt << 4) + l15] = o[r];
            }
            __syncthreads();
            for (int oo = t; oo < NT * EMB; oo += THREADS) {
                const int r = oo >> 7, e = oo & 127;
                float s = (h == 0) ? R_b[e] : 0.f;
                const float* rw = R_w + (size_t)e * (NH * DH) + h * DH;
                const float* oh = sOH + r * DH;
                #pragma unroll
                for (int c = 0; c < DH; ++c) s += oh[c] * rw[c];
                atomicAdd(&out[((size_t)b * NT + r) * EMB + e], s);
            }
        }
    }
}

// rproj4: MFMA GEMM. out[51200x128] = cat[51200x256] @ R_w[128x256]^T + R_b.
// B fragments from pre-split R planes (L2-hot); A split on the fly.
__global__ __launch_bounds__(256, 4) void rproj4(
    const float* __restrict__ cat, const unsigned short* __restrict__ rhi,
    const float* __restrict__ R_b, float* __restrict__ out)
{
    const int t = threadIdx.x;
    const int lane = t & 63, wave = t >> 6;
    const int l15 = lane & 15, g = lane >> 4;
    const int m0 = blockIdx.x * 64 + wave * 16;
    const float* ap = cat + (size_t)(m0 + l15) * 256 + (g << 3);
    const unsigned short* rlo = rhi + (WS_R_LO - WS_R_HI);

    f4acc acc[8];
    #pragma unroll
    for (int nt = 0; nt < 8; ++nt) {
        const float rb = R_b[nt * 16 + l15];
        acc[nt][0] = rb; acc[nt][1] = rb; acc[nt][2] = rb; acc[nt][3] = rb;
    }
    #pragma unroll
    for (int ks = 0; ks < 8; ++ks) {
        bh8 ah, al;
        split8(ap + ks * 32, ah, al);
        #pragma unroll
        for (int nt = 0; nt < 8; ++nt) {
            const size_t o = (size_t)(nt * 16 + l15) * 256 + ks * 32 + (g << 3);
            const bh8 bh_ = *reinterpret_cast<const bh8*>(rhi + o);
            const bh8 bl_ = *reinterpret_cast<const bh8*>(rlo + o);
            acc[nt] = mfma_bf16(ah, bh_, acc[nt]);
            acc[nt] = mfma_bf16(al, bh_, acc[nt]);
            acc[nt] = mfma_bf16(ah, bl_, acc[nt]);
        }
    }
    const int row = m0 + (g << 2);
    #pragma unroll
    for (int nt = 0; nt < 8; ++nt) {
        #pragma unroll
        for (int r = 0; r < 4; ++r)
            out[(size_t)(row + r) * EMB + nt * 16 + l15] = acc[nt][r];
    }
}

extern "C" void kernel_launch(void* const* d_in, const int* in_sizes, int n_in,
                              void* d_out, int out_size, void* d_ws, size_t ws_size,
                              hipStream_t stream)
{
    const float* gq   = (const float*)d_in[0];
    const float* gk   = (const float*)d_in[1];
    const float* gv   = (const float*)d_in[2];
    const float* At_w = (const float*)d_in[3];
    const float* At_b = (const float*)d_in[4];
    const float* Ac_w = (const float*)d_in[5];
    const float* Ac_b = (const float*)d_in[6];
    const float* Bc_w = (const float*)d_in[7];
    const float* Bc_b = (const float*)d_in[8];
    const float* pb   = (const float*)d_in[9];
    const float* R_w  = (const float*)d_in[10];
    const float* R_b  = (const float*)d_in[11];

    const int nbat = in_sizes[0] / (NT * EMB);   // 1024
    float* out = (float*)d_out;
    float* att = out + (size_t)nbat * NT * EMB;

    const size_t ws_need = WS_CAT_B + (size_t)nbat * NT * NH * DH * sizeof(float);
    const int nwg = nbat * NH;

    if (ws_size >= ws_need) {
        unsigned short* wsp = (unsigned short*)d_ws;
        float* cat = (float*)((char*)d_ws + WS_CAT_B);
        wprep<<<32, 512, 0, stream>>>(At_w, Ac_w, Bc_w, R_w, wsp);
        attn_mfma<1><<<nwg, THREADS, 0, stream>>>(
            gq, gk, gv, At_w, At_b, Ac_w, Ac_b, Bc_w, Bc_b, pb, R_w, R_b,
            out, att, cat, wsp, nbat);
        rproj4<<<(nbat * NT) / 64, 256, 0, stream>>>(cat, wsp + WS_R_HI, R_b, out);
    } else {
        hipMemsetAsync(d_out, 0, (size_t)nbat * NT * EMB * sizeof(float), stream);
        attn_mfma<0><<<nwg, THREADS, 0, stream>>>(
            gq, gk, gv, At_w, At_b, Ac_w, Ac_b, Bc_w, Bc_b, pb, R_w, R_b,
            out, att, nullptr, nullptr, nbat);
    }
}

// Round 9
// 548.206 us; speedup vs baseline: 1.3692x; 1.2122x over previous
//
#include <hip/hip_runtime.h>

// ---------------------------------------------------------------------------
// Cosine-similarity MHA, round 9: 3-kernel structure.
//  projn: GEMM q-hat/k-hat (normalized, bf16) + v for all batches -> ws.
//         X read once (was 16x), W from presplit planes, 1-term bf16.
//  attn2: per (b,h): load qhat/khat/v -> scores -> no-max softmax -> att,
//         PV -> cat. No projections, no norms, 4 barriers.
//  rproj4: split-bf16 MFMA GEMM out = cat @ R_w^T + R_b.
// Tiers: ws >= ~289MB new path; >= ~53MB round-8 path; else atomic fallback.
// ---------------------------------------------------------------------------

#define NT 50
#define NC 200
#define EMB 128
#define DH 32
#define NH 8
#define THREADS 512
#define LOG2E 1.44269504088896340736f

#define WS_PROJ_LO 98304u       // short offset of proj lo plane
#define WS_R_HI    196608u      // short offset of R hi plane
#define WS_R_LO    229376u      // short offset of R lo plane
#define WS_PLANES_B 524288u     // bytes: end of weight planes

typedef __attribute__((ext_vector_type(4))) float f4acc;
typedef __attribute__((ext_vector_type(8))) short bh8;

__device__ __forceinline__ f4acc mfma_bf16(bh8 a, bh8 b, f4acc c) {
    return __builtin_amdgcn_mfma_f32_16x16x32_bf16(a, b, c, 0, 0, 0);
}

__device__ __forceinline__ unsigned short bf16rne(float x) {
    unsigned int u = __float_as_uint(x);
    u += 0x7FFFu + ((u >> 16) & 1u);
    return (unsigned short)(u >> 16);
}

// 8 f32 -> bf16 RNE (packed); pair order identical for A and B operands.
__device__ __forceinline__ bh8 cvt8(const float* __restrict__ p) {
    float4 x0 = *reinterpret_cast<const float4*>(p);
    float4 x1 = *reinterpret_cast<const float4*>(p + 4);
    float xs[8] = {x0.x, x0.y, x0.z, x0.w, x1.x, x1.y, x1.z, x1.w};
    union { unsigned int w[4]; bh8 v; } H;
    #pragma unroll
    for (int i = 0; i < 4; ++i)
        asm("v_cvt_pk_bf16_f32 %0, %1, %2"
            : "=v"(H.w[i]) : "v"(xs[2 * i]), "v"(xs[2 * i + 1]));
    return H.v;
}

__device__ __forceinline__ void split8(const float* __restrict__ p, bh8& hi, bh8& lo) {
    float4 x0 = *reinterpret_cast<const float4*>(p);
    float4 x1 = *reinterpret_cast<const float4*>(p + 4);
    float xs[8] = {x0.x, x0.y, x0.z, x0.w, x1.x, x1.y, x1.z, x1.w};
    union { unsigned int w[4]; bh8 v; } H, L;
    #pragma unroll
    for (int i = 0; i < 4; ++i) {
        const float a = xs[2 * i], b = xs[2 * i + 1];
        unsigned int hw, lw;
        asm("v_cvt_pk_bf16_f32 %0, %1, %2" : "=v"(hw) : "v"(a), "v"(b));
        const float ha = __uint_as_float(hw << 16);
        const float hb = __uint_as_float(hw & 0xFFFF0000u);
        const float la = a - ha, lb = b - hb;
        asm("v_cvt_pk_bf16_f32 %0, %1, %2" : "=v"(lw) : "v"(la), "v"(lb));
        H.w[i] = hw; L.w[i] = lw;
    }
    hi = H.v; lo = L.v;
}

// ---- wprep: split all weights into hi/lo bf16 planes in ws ----
__global__ __launch_bounds__(512) void wprep(
    const float* __restrict__ At_w, const float* __restrict__ Ac_w,
    const float* __restrict__ Bc_w, const float* __restrict__ R_w,
    unsigned short* __restrict__ ws)
{
    const int u = blockIdx.x * 512 + threadIdx.x;     // 16384 units of 8 elems
    bh8 h8, l8;
    if (u < 12288) {                                  // proj: [3][256][128]
        const int p = u >> 12, rem = u & 4095;
        const int col = rem >> 4, e0 = (rem & 15) << 3;
        const float* W = (p == 0) ? At_w : (p == 1) ? Ac_w : Bc_w;
        split8(W + (size_t)col * 128 + e0, h8, l8);
        const size_t o = ((size_t)p * 256 + col) * 128 + e0;
        *reinterpret_cast<bh8*>(ws + o) = h8;
        *reinterpret_cast<bh8*>(ws + WS_PROJ_LO + o) = l8;
    } else {                                          // R: [128][256]
        const int u2 = u - 12288;
        const int e = u2 >> 5, k0 = (u2 & 31) << 3;
        split8(R_w + (size_t)e * 256 + k0, h8, l8);
        const size_t o = (size_t)e * 256 + k0;
        *reinterpret_cast<bh8*>(ws + WS_R_HI + o) = h8;
        *reinterpret_cast<bh8*>(ws + WS_R_LO + o) = l8;
    }
}

// ---- projn: q-hat/k-hat (normalized) + v, bf16, all batches ----
// grid = nbat*3 (batch, type), 512 thr. Wave w owns head w; per m-tile:
// A-frag from X (1-term cvt), B-frags hoisted from plane, 8 MFMA, in-register
// row-norm over the head's 32 cols via 16-lane shfl, bf16 write.
__global__ __launch_bounds__(512, 4) void projn(
    const float* __restrict__ gq, const float* __restrict__ gk,
    const float* __restrict__ gv,
    const float* __restrict__ At_b, const float* __restrict__ Ac_b,
    const float* __restrict__ Bc_b,
    const unsigned short* __restrict__ wsp,
    unsigned short* __restrict__ qh, unsigned short* __restrict__ kh,
    unsigned short* __restrict__ vh)
{
    const int t = threadIdx.x;
    const int blk = blockIdx.x;
    const int b = blk / 3, ty = blk - b * 3;
    const float* X  = (ty == 0) ? gq : (ty == 1) ? gk : gv;
    const float* Bv = (ty == 0) ? At_b : (ty == 1) ? Ac_b : Bc_b;
    const int nrows = (ty == 0) ? NT : NC;
    unsigned short* O = (ty == 0) ? qh + (size_t)b * (NT * 256)
                      : (ty == 1) ? kh + (size_t)b * (NC * 256)
                                  : vh + (size_t)b * (NC * 256);
    const unsigned short* Wp = wsp + (size_t)ty * 32768;
    const bool donorm = (ty < 2);
    const int nmt = (ty == 0) ? 4 : 13;

    const int lane = t & 63, w = t >> 6, l15 = lane & 15, g = lane >> 4;
    const int c0i = w * 32 + l15, c1i = c0i + 16;

    bh8 bf0[4], bf1[4];
    #pragma unroll
    for (int ks = 0; ks < 4; ++ks) {
        bf0[ks] = *reinterpret_cast<const bh8*>(Wp + (size_t)c0i * 128 + ks * 32 + (g << 3));
        bf1[ks] = *reinterpret_cast<const bh8*>(Wp + (size_t)c1i * 128 + ks * 32 + (g << 3));
    }
    const float bias0 = Bv[c0i], bias1 = Bv[c1i];

    for (int mt = 0; mt < nmt; ++mt) {
        int ar = mt * 16 + l15; if (ar > nrows - 1) ar = nrows - 1;
        const float* ap = X + (size_t)b * nrows * EMB + (size_t)ar * EMB + (g << 3);
        f4acc a0 = {bias0, bias0, bias0, bias0};
        f4acc a1 = {bias1, bias1, bias1, bias1};
        #pragma unroll
        for (int ks = 0; ks < 4; ++ks) {
            const bh8 xv = cvt8(ap + ks * 32);
            a0 = mfma_bf16(xv, bf0[ks], a0);
            a1 = mfma_bf16(xv, bf1[ks], a1);
        }
        if (donorm) {
            float s[4];
            #pragma unroll
            for (int r = 0; r < 4; ++r) s[r] = a0[r] * a0[r] + a1[r] * a1[r];
            #pragma unroll
            for (int r = 0; r < 4; ++r) {
                s[r] += __shfl_xor(s[r], 1);
                s[r] += __shfl_xor(s[r], 2);
                s[r] += __shfl_xor(s[r], 4);
                s[r] += __shfl_xor(s[r], 8);
            }
            #pragma unroll
            for (int r = 0; r < 4; ++r) {
                const float rs = rsqrtf(fmaxf(s[r], 1e-12f));
                a0[r] *= rs; a1[r] *= rs;
            }
        }
        #pragma unroll
        for (int r = 0; r < 4; ++r) {
            const int row = mt * 16 + (g << 2) + r;
            if (row < nrows) {
                O[(size_t)row * 256 + c0i] = bf16rne(a0[r]);
                O[(size_t)row * 256 + c1i] = bf16rne(a1[r]);
            }
        }
    }
}

// ---- attn2: scores + softmax + att + PV + cat, from prestaged bf16 ----
// LDS (bytes): sVT 0..14848, sK 14848..30848, sQ 30848..35968,
// sP alias 14848..38048, spb 38048..38848, sSm 39360..39872.
__global__ __launch_bounds__(512, 6) void attn2(
    const unsigned short* __restrict__ qh, const unsigned short* __restrict__ kh,
    const unsigned short* __restrict__ vh, const float* __restrict__ pos_bias,
    float* __restrict__ att, float* __restrict__ cat, int nbat)
{
    const int t = threadIdx.x;
    const int p = blockIdx.x;
    const int chunk = (nbat * NH) >> 3;
    const int lj = (p & 7) * chunk + (p >> 3);
    const int b = lj >> 3, h = lj & 7;
    const int lane = t & 63, wave = t >> 6, l15 = lane & 15, g = lane >> 4;

    __shared__ __align__(16) unsigned char smem[39872];
    unsigned short* sVT = reinterpret_cast<unsigned short*>(smem);
    unsigned short* sK  = reinterpret_cast<unsigned short*>(smem + 14848);
    unsigned short* sQ  = reinterpret_cast<unsigned short*>(smem + 30848);
    unsigned short* sP  = reinterpret_cast<unsigned short*>(smem + 14848);
    float* spb = reinterpret_cast<float*>(smem + 38048);
    float* sSm = reinterpret_cast<float*>(smem + 39360);

    // ---- P0: stage qhat/khat/v, zero sVT K-pad, pos_bias*log2e ----
    if (t < 448) {
        unsigned int* v32 = reinterpret_cast<unsigned int*>(sVT);
        const int col = t / 14, i = t - col * 14;
        v32[col * 116 + 100 + i] = 0u;
    }
    if (t < NC) spb[t] = pos_bias[t] * LOG2E;
    if (t < 200) {
        const int row = t >> 2, q = t & 3;
        *reinterpret_cast<bh8*>(sQ + row * 40 + q * 8) =
            *reinterpret_cast<const bh8*>(qh + (size_t)b * (NT * 256) + row * 256 + h * 32 + q * 8);
    }
    for (int u = t; u < 800; u += THREADS) {
        const int row = u >> 2, q = u & 3;
        *reinterpret_cast<bh8*>(sK + row * 40 + q * 8) =
            *reinterpret_cast<const bh8*>(kh + (size_t)b * (NC * 256) + row * 256 + h * 32 + q * 8);
    }
    for (int u = t; u < 800; u += THREADS) {
        const int row = u >> 2, q = u & 3;
        const bh8 vv = *reinterpret_cast<const bh8*>(
            vh + (size_t)b * (NC * 256) + row * 256 + h * 32 + q * 8);
        #pragma unroll
        for (int e = 0; e < 8; ++e)
            sVT[(q * 8 + e) * 232 + row] = (unsigned short)vv[e];
    }
    __syncthreads();

    // ---- P3: scores = qhat.khat (1 MFMA + 4 FMA per tile) ----
    const int mt = wave & 3, hf = wave >> 2;
    const int m0 = mt << 4;
    const int row64 = m0 + (g << 2);
    int arow = m0 + l15; if (arow > NT - 1) arow = NT - 1;
    const bh8 aq = *reinterpret_cast<const bh8*>(sQ + arow * 40 + (g << 3));

    f4acc acc[7];
    #pragma unroll
    for (int i = 0; i < 7; ++i) {
        const int nt = hf * 7 + i;
        if (nt < 13) {
            const int col = (nt << 4) + l15;
            const int bc = (col < NC) ? col : (NC - 1);
            const bh8 bk = *reinterpret_cast<const bh8*>(sK + bc * 40 + (g << 3));
            f4acc c = {0.f, 0.f, 0.f, 0.f};
            c = mfma_bf16(aq, bk, c);
            const float pbl = spb[bc];
            #pragma unroll
            for (int r = 0; r < 4; ++r)
                acc[i][r] = (col < NC) ? fmaf(c[r], LOG2E, pbl) : -1e30f;
        }
    }
    __syncthreads();                 // sK/sQ dead; sP region live

    // ---- P4: no-max softmax (|score*log2e| <= 1.45) ----
    {
        unsigned int* p32 = reinterpret_cast<unsigned int*>(sP);
        for (int tt = t; tt < 700; tt += THREADS) {    // sP K-pad zero
            const int row = tt / 14, i = tt - row * 14;
            p32[row * 116 + 100 + i] = 0u;
        }
    }
    {
        float sl[4] = {0.f, 0.f, 0.f, 0.f};
        #pragma unroll
        for (int i = 0; i < 7; ++i) {
            if (hf * 7 + i < 13) {
                #pragma unroll
                for (int r = 0; r < 4; ++r) {
                    const float e = __builtin_exp2f(acc[i][r]);
                    acc[i][r] = e;
                    sl[r] += e;
                }
            }
        }
        #pragma unroll
        for (int r = 0; r < 4; ++r) {
            sl[r] += __shfl_xor(sl[r], 1);
            sl[r] += __shfl_xor(sl[r], 2);
            sl[r] += __shfl_xor(sl[r], 4);
            sl[r] += __shfl_xor(sl[r], 8);
        }
        if (l15 == 0) {
            #pragma unroll
            for (int r = 0; r < 4; ++r) sSm[hf * 64 + row64 + r] = sl[r];
        }
    }
    __syncthreads();

    // ---- P4c: normalize, write att (f32 global) + P (bf16 LDS) ----
    {
        float inv[4];
        #pragma unroll
        for (int r = 0; r < 4; ++r)
            inv[r] = 1.0f / (sSm[row64 + r] + sSm[64 + row64 + r]);
        float* attb = att + (size_t)(b * NH + h) * NT * NC;
        #pragma unroll
        for (int i = 0; i < 7; ++i) {
            const int nt = hf * 7 + i;
            if (nt < 13) {
                const int col = (nt << 4) + l15;
                if (col < NC) {
                    #pragma unroll
                    for (int r = 0; r < 4; ++r) {
                        const int row = row64 + r;
                        if (row < NT) {
                            const float v = acc[i][r] * inv[r];
                            attb[row * NC + col] = v;
                            sP[row * 232 + col] = bf16rne(v);
                        }
                    }
                }
            }
        }
    }
    __syncthreads();

    // ---- P5: PV (bf16 MFMA, K=224 zero-padded) + cat write ----
    {
        const int pnt = wave >> 2;
        const unsigned short* pA = sP + arow * 232;
        const unsigned short* pB = sVT + (size_t)((pnt << 4) + l15) * 232;
        f4acc o = {0.f, 0.f, 0.f, 0.f};
        #pragma unroll
        for (int ks = 0; ks < 7; ++ks) {
            const bh8 a = *reinterpret_cast<const bh8*>(pA + ks * 32 + (g << 3));
            const bh8 v = *reinterpret_cast<const bh8*>(pB + ks * 32 + (g << 3));
            o = mfma_bf16(a, v, o);
        }
        float* wsb = cat + (size_t)b * (NT * NH * DH) + h * DH;
        #pragma unroll
        for (int r = 0; r < 4; ++r) {
            const int row = row64 + r;
            if (row < NT) wsb[(size_t)row * (NH * DH) + (pnt << 4) + l15] = o[r];
        }
    }
}

// ================= round-8 kernel retained as tier-2/3 fallback =============
template <int WSP>
__global__ __launch_bounds__(THREADS, 4) void attn_mfma(
    const float* __restrict__ gq, const float* __restrict__ gk,
    const float* __restrict__ gv,
    const float* __restrict__ At_w, const float* __restrict__ At_b,
    const float* __restrict__ Ac_w, const float* __restrict__ Ac_b,
    const float* __restrict__ Bc_w, const float* __restrict__ Bc_b,
    const float* __restrict__ pos_bias,
    const float* __restrict__ R_w, const float* __restrict__ R_b,
    float* __restrict__ out, float* __restrict__ att,
    float* __restrict__ cat, const unsigned short* __restrict__ wsp,
    int nbat)
{
    const int t = threadIdx.x;
    const int p = blockIdx.x;
    const int chunk = (nbat * NH) >> 3;
    const int lj = (p & 7) * chunk + (p >> 3);
    const int b = lj >> 3;
    const int h = lj & 7;
    const int lane = t & 63, wave = t >> 6;
    const int l15 = lane & 15, g = lane >> 4;

    __shared__ __align__(16) unsigned char smem[39872];
    unsigned short* sVT = reinterpret_cast<unsigned short*>(smem);
    unsigned short* sK  = reinterpret_cast<unsigned short*>(smem + 14848);
    unsigned short* sQ  = reinterpret_cast<unsigned short*>(smem + 30848);
    unsigned short* sP  = reinterpret_cast<unsigned short*>(smem + 14848);
    float* spb = reinterpret_cast<float*>(smem + 38048);
    float* sSm = reinterpret_cast<float*>(smem + 39360);

    if (t < 448) {
        unsigned int* v32 = reinterpret_cast<unsigned int*>(sVT);
        const int col = t / 14, i = t - col * 14;
        v32[col * 116 + 100 + i] = 0u;
    }
    if (t < NC) spb[t] = pos_bias[t] * LOG2E;

    {
        const int s0 = (wave * 60) >> 3;
        const int s1 = ((wave + 1) * 60) >> 3;
        int cp = -1, cn = -1;
        bh8 wh[4], wl[4];
        float bias = 0.f;
        for (int id = s0; id < s1; ++id) {
            int pidx, nt, mt2;
            if (id < 8)       { pidx = 0; nt = id >> 2; mt2 = id & 3; }
            else if (id < 34) { int j = id - 8;  pidx = 1; nt = j / 13; mt2 = j - nt * 13; }
            else              { int j = id - 34; pidx = 2; nt = j / 13; mt2 = j - nt * 13; }
            const int col = (nt << 4) + l15;
            if (pidx != cp || nt != cn) {
                cp = pidx; cn = nt;
                const int gcol = h * DH + col;
                if (WSP) {
                    const unsigned short* whp =
                        wsp + ((size_t)pidx * 256 + gcol) * 128 + (g << 3);
                    const unsigned short* wlp = whp + WS_PROJ_LO;
                    #pragma unroll
                    for (int ks = 0; ks < 4; ++ks) {
                        wh[ks] = *reinterpret_cast<const bh8*>(whp + ks * 32);
                        wl[ks] = *reinterpret_cast<const bh8*>(wlp + ks * 32);
                    }
                } else {
                    const float* Wm = (pidx == 0) ? At_w : (pidx == 1) ? Ac_w : Bc_w;
                    const float* bp = Wm + (size_t)gcol * EMB + (g << 3);
                    #pragma unroll
                    for (int ks = 0; ks < 4; ++ks) split8(bp + ks * 32, wh[ks], wl[ks]);
                }
                const float* Wb = (pidx == 0) ? At_b : (pidx == 1) ? Ac_b : Bc_b;
                bias = Wb[gcol];
            }
            const int nrows = (pidx == 0) ? NT : NC;
            const float* Xb = (pidx == 0) ? gq : (pidx == 1) ? gk : gv;
            int ar = mt2 * 16 + l15; if (ar > nrows - 1) ar = nrows - 1;
            const float* ap = Xb + (size_t)b * nrows * EMB + (size_t)ar * EMB + (g << 3);
            f4acc acc2 = {bias, bias, bias, bias};
            #pragma unroll
            for (int ks = 0; ks < 4; ++ks) {
                bh8 xh, xl;
                split8(ap + ks * 32, xh, xl);
                acc2 = mfma_bf16(xh, wh[ks], acc2);
                acc2 = mfma_bf16(xl, wh[ks], acc2);
                acc2 = mfma_bf16(xh, wl[ks], acc2);
            }
            #pragma unroll
            for (int r = 0; r < 4; ++r) {
                const int row = mt2 * 16 + (g << 2) + r;
                if (row < nrows) {
                    const unsigned short hv = bf16rne(acc2[r]);
                    if (pidx == 0)      sQ[row * 40 + col] = hv;
                    else if (pidx == 1) sK[row * 40 + col] = hv;
                    else                sVT[col * 232 + row] = hv;
                }
            }
        }
    }
    __syncthreads();

    if (t < 250) {
        unsigned short* rowp = (t < 200) ? (sK + t * 40) : (sQ + (t - 200) * 40);
        unsigned int* w32 = reinterpret_cast<unsigned int*>(rowp);
        unsigned int w[16];
        #pragma unroll
        for (int i = 0; i < 16; ++i) w[i] = w32[i];
        float s = 0.f;
        #pragma unroll
        for (int i = 0; i < 16; ++i) {
            const float a = __uint_as_float(w[i] << 16);
            const float c = __uint_as_float(w[i] & 0xFFFF0000u);
            s += a * a + c * c;
        }
        const float rs = rsqrtf(fmaxf(s, 1e-12f));
        #pragma unroll
        for (int i = 0; i < 16; ++i) {
            const float a = __uint_as_float(w[i] << 16) * rs;
            const float c = __uint_as_float(w[i] & 0xFFFF0000u) * rs;
            unsigned int pw;
            asm("v_cvt_pk_bf16_f32 %0, %1, %2" : "=v"(pw) : "v"(a), "v"(c));
            w32[i] = pw;
        }
    }
    __syncthreads();

    const int mt = wave & 3, hf = wave >> 2;
    const int m0 = mt << 4;
    const int row64 = m0 + (g << 2);
    int arow = m0 + l15; if (arow > NT - 1) arow = NT - 1;
    const bh8 aq = *reinterpret_cast<const bh8*>(sQ + arow * 40 + (g << 3));

    f4acc acc[7];
    #pragma unroll
    for (int i = 0; i < 7; ++i) {
        const int nt = hf * 7 + i;
        if (nt < 13) {
            const int col = (nt << 4) + l15;
            const int bc = (col < NC) ? col : (NC - 1);
            const bh8 bk = *reinterpret_cast<const bh8*>(sK + bc * 40 + (g << 3));
            f4acc c = {0.f, 0.f, 0.f, 0.f};
            c = mfma_bf16(aq, bk, c);
            const float pbl = spb[bc];
            #pragma unroll
            for (int r = 0; r < 4; ++r)
                acc[i][r] = (col < NC) ? fmaf(c[r], LOG2E, pbl) : -1e30f;
        }
    }
    __syncthreads();

    {
        unsigned int* p32 = reinterpret_cast<unsigned int*>(sP);
        for (int tt = t; tt < 700; tt += THREADS) {
            const int row = tt / 14, i = tt - row * 14;
            p32[row * 116 + 100 + i] = 0u;
        }
    }
    {
        float sl[4] = {0.f, 0.f, 0.f, 0.f};
        #pragma unroll
        for (int i = 0; i < 7; ++i) {
            if (hf * 7 + i < 13) {
                #pragma unroll
                for (int r = 0; r < 4; ++r) {
                    const float e = __builtin_exp2f(acc[i][r]);
                    acc[i][r] = e;
                    sl[r] += e;
                }
            }
        }
        #pragma unroll
        for (int r = 0; r < 4; ++r) {
            sl[r] += __shfl_xor(sl[r], 1);
            sl[r] += __shfl_xor(sl[r], 2);
            sl[r] += __shfl_xor(sl[r], 4);
            sl[r] += __shfl_xor(sl[r], 8);
        }
        if (l15 == 0) {
            #pragma unroll
            for (int r = 0; r < 4; ++r) sSm[hf * 64 + row64 + r] = sl[r];
        }
    }
    __syncthreads();

    {
        float inv[4];
        #pragma unroll
        for (int r = 0; r < 4; ++r)
            inv[r] = 1.0f / (sSm[row64 + r] + sSm[64 + row64 + r]);
        float* attb = att + (size_t)(b * NH + h) * NT * NC;
        #pragma unroll
        for (int i = 0; i < 7; ++i) {
            const int nt = hf * 7 + i;
            if (nt < 13) {
                const int col = (nt << 4) + l15;
                if (col < NC) {
                    #pragma unroll
                    for (int r = 0; r < 4; ++r) {
                        const int row = row64 + r;
                        if (row < NT) {
                            const float v = acc[i][r] * inv[r];
                            attb[row * NC + col] = v;
                            sP[row * 232 + col] = bf16rne(v);
                        }
                    }
                }
            }
        }
    }
    __syncthreads();

    {
        const int pnt = wave >> 2;
        const unsigned short* pA = sP + arow * 232;
        const unsigned short* pB = sVT + (size_t)((pnt << 4) + l15) * 232;
        f4acc o = {0.f, 0.f, 0.f, 0.f};
        #pragma unroll
        for (int ks = 0; ks < 7; ++ks) {
            const bh8 a = *reinterpret_cast<const bh8*>(pA + ks * 32 + (g << 3));
            const bh8 v = *reinterpret_cast<const bh8*>(pB + ks * 32 + (g << 3));
            o = mfma_bf16(a, v, o);
        }
        if (WSP) {
            float* wsb = cat + (size_t)b * (NT * NH * DH) + h * DH;
            #pragma unroll
            for (int r = 0; r < 4; ++r) {
                const int row = row64 + r;
                if (row < NT) wsb[(size_t)row * (NH * DH) + (pnt << 4) + l15] = o[r];
            }
        } else {
            __syncthreads();
            float* sOH = reinterpret_cast<float*>(smem);
            #pragma unroll
            for (int r = 0; r < 4; ++r) {
                const int row = row64 + r;
                if (row < NT) sOH[row * DH + (pnt << 4) + l15] = o[r];
            }
            __syncthreads();
            for (int oo = t; oo < NT * EMB; oo += THREADS) {
                const int r = oo >> 7, e = oo & 127;
                float s = (h == 0) ? R_b[e] : 0.f;
                const float* rw = R_w + (size_t)e * (NH * DH) + h * DH;
                const float* oh = sOH + r * DH;
                #pragma unroll
                for (int c = 0; c < DH; ++c) s += oh[c] * rw[c];
                atomicAdd(&out[((size_t)b * NT + r) * EMB + e], s);
            }
        }
    }
}

// rproj4: MFMA GEMM. out[51200x128] = cat[51200x256] @ R_w[128x256]^T + R_b.
__global__ __launch_bounds__(256, 4) void rproj4(
    const float* __restrict__ cat, const unsigned short* __restrict__ rhi,
    const float* __restrict__ R_b, float* __restrict__ out)
{
    const int t = threadIdx.x;
    const int lane = t & 63, wave = t >> 6;
    const int l15 = lane & 15, g = lane >> 4;
    const int m0 = blockIdx.x * 64 + wave * 16;
    const float* ap = cat + (size_t)(m0 + l15) * 256 + (g << 3);
    const unsigned short* rlo = rhi + (WS_R_LO - WS_R_HI);

    f4acc acc[8];
    #pragma unroll
    for (int nt = 0; nt < 8; ++nt) {
        const float rb = R_b[nt * 16 + l15];
        acc[nt][0] = rb; acc[nt][1] = rb; acc[nt][2] = rb; acc[nt][3] = rb;
    }
    #pragma unroll
    for (int ks = 0; ks < 8; ++ks) {
        bh8 ah, al;
        split8(ap + ks * 32, ah, al);
        #pragma unroll
        for (int nt = 0; nt < 8; ++nt) {
            const size_t o = (size_t)(nt * 16 + l15) * 256 + ks * 32 + (g << 3);
            const bh8 bh_ = *reinterpret_cast<const bh8*>(rhi + o);
            const bh8 bl_ = *reinterpret_cast<const bh8*>(rlo + o);
            acc[nt] = mfma_bf16(ah, bh_, acc[nt]);
            acc[nt] = mfma_bf16(al, bh_, acc[nt]);
            acc[nt] = mfma_bf16(ah, bl_, acc[nt]);
        }
    }
    const int row = m0 + (g << 2);
    #pragma unroll
    for (int nt = 0; nt < 8; ++nt) {
        #pragma unroll
        for (int r = 0; r < 4; ++r)
            out[(size_t)(row + r) * EMB + nt * 16 + l15] = acc[nt][r];
    }
}

extern "C" void kernel_launch(void* const* d_in, const int* in_sizes, int n_in,
                              void* d_out, int out_size, void* d_ws, size_t ws_size,
                              hipStream_t stream)
{
    const float* gq   = (const float*)d_in[0];
    const float* gk   = (const float*)d_in[1];
    const float* gv   = (const float*)d_in[2];
    const float* At_w = (const float*)d_in[3];
    const float* At_b = (const float*)d_in[4];
    const float* Ac_w = (const float*)d_in[5];
    const float* Ac_b = (const float*)d_in[6];
    const float* Bc_w = (const float*)d_in[7];
    const float* Bc_b = (const float*)d_in[8];
    const float* pb   = (const float*)d_in[9];
    const float* R_w  = (const float*)d_in[10];
    const float* R_b  = (const float*)d_in[11];

    const int nbat = in_sizes[0] / (NT * EMB);   // 1024
    float* out = (float*)d_out;
    float* att = out + (size_t)nbat * NT * EMB;

    const size_t qB   = (size_t)nbat * NT * 256 * 2;
    const size_t kB   = (size_t)nbat * NC * 256 * 2;
    const size_t catB = (size_t)nbat * NT * NH * DH * sizeof(float);
    const size_t need3 = WS_PLANES_B + qB + 2 * kB + catB;   // ~289 MB
    const size_t need2 = WS_PLANES_B + catB;                 // ~53 MB
    const int nwg = nbat * NH;

    if (ws_size >= need3) {
        unsigned short* wsp = (unsigned short*)d_ws;
        unsigned short* qh = (unsigned short*)((char*)d_ws + WS_PLANES_B);
        unsigned short* kh = (unsigned short*)((char*)d_ws + WS_PLANES_B + qB);
        unsigned short* vh = (unsigned short*)((char*)d_ws + WS_PLANES_B + qB + kB);
        float* cat = (float*)((char*)d_ws + WS_PLANES_B + qB + 2 * kB);
        wprep<<<32, 512, 0, stream>>>(At_w, Ac_w, Bc_w, R_w, wsp);
        projn<<<nbat * 3, 512, 0, stream>>>(gq, gk, gv, At_b, Ac_b, Bc_b,
                                            wsp, qh, kh, vh);
        attn2<<<nwg, THREADS, 0, stream>>>(qh, kh, vh, pb, att, cat, nbat);
        rproj4<<<(nbat * NT) / 64, 256, 0, stream>>>(cat, wsp + WS_R_HI, R_b, out);
    } else if (ws_size >= need2) {
        unsigned short* wsp = (unsigned short*)d_ws;
        float* cat = (float*)((char*)d_ws + WS_PLANES_B);
        wprep<<<32, 512, 0, stream>>>(At_w, Ac_w, Bc_w, R_w, wsp);
        attn_mfma<1><<<nwg, THREADS, 0, stream>>>(
            gq, gk, gv, At_w, At_b, Ac_w, Ac_b, Bc_w, Bc_b, pb, R_w, R_b,
            out, att, cat, wsp, nbat);
        rproj4<<<(nbat * NT) / 64, 256, 0, stream>>>(cat, wsp + WS_R_HI, R_b, out);
    } else {
        hipMemsetAsync(d_out, 0, (size_t)nbat * NT * EMB * sizeof(float), stream);
        attn_mfma<0><<<nwg, THREADS, 0, stream>>>(
            gq, gk, gv, At_w, At_b, Ac_w, Ac_b, Bc_w, Bc_b, pb, R_w, R_b,
            out, att, nullptr, nullptr, nbat);
    }
}

// Round 10
// 532.533 us; speedup vs baseline: 1.4095x; 1.0294x over previous
//
#include <hip/hip_runtime.h>

// ---------------------------------------------------------------------------
// Cosine-similarity MHA, round 10:
//  projn: flattened — block = (batch, type, m-tile), 30720 blocks. X tile
//         staged coalesced into LDS once; wave = head; no serial m-tile loop,
//         no redundant global X reads. q-hat/k-hat normalized in-register.
//  attn2: unchanged (scores -> no-max softmax -> att + PV -> cat).
//  rproj4: unchanged split-bf16 MFMA GEMM.
// Tiers: ws >= ~289MB new path; >= ~53MB round-8 path; else atomic fallback.
// ---------------------------------------------------------------------------

#define NT 50
#define NC 200
#define EMB 128
#define DH 32
#define NH 8
#define THREADS 512
#define LOG2E 1.44269504088896340736f

#define WS_PROJ_LO 98304u       // short offset of proj lo plane
#define WS_R_HI    196608u      // short offset of R hi plane
#define WS_R_LO    229376u      // short offset of R lo plane
#define WS_PLANES_B 524288u     // bytes: end of weight planes

typedef __attribute__((ext_vector_type(4))) float f4acc;
typedef __attribute__((ext_vector_type(8))) short bh8;

__device__ __forceinline__ f4acc mfma_bf16(bh8 a, bh8 b, f4acc c) {
    return __builtin_amdgcn_mfma_f32_16x16x32_bf16(a, b, c, 0, 0, 0);
}

__device__ __forceinline__ unsigned short bf16rne(float x) {
    unsigned int u = __float_as_uint(x);
    u += 0x7FFFu + ((u >> 16) & 1u);
    return (unsigned short)(u >> 16);
}

// 8 f32 -> bf16 RNE (packed); pair order identical for A and B operands.
__device__ __forceinline__ bh8 cvt8(const float* __restrict__ p) {
    float4 x0 = *reinterpret_cast<const float4*>(p);
    float4 x1 = *reinterpret_cast<const float4*>(p + 4);
    float xs[8] = {x0.x, x0.y, x0.z, x0.w, x1.x, x1.y, x1.z, x1.w};
    union { unsigned int w[4]; bh8 v; } H;
    #pragma unroll
    for (int i = 0; i < 4; ++i)
        asm("v_cvt_pk_bf16_f32 %0, %1, %2"
            : "=v"(H.w[i]) : "v"(xs[2 * i]), "v"(xs[2 * i + 1]));
    return H.v;
}

__device__ __forceinline__ void split8(const float* __restrict__ p, bh8& hi, bh8& lo) {
    float4 x0 = *reinterpret_cast<const float4*>(p);
    float4 x1 = *reinterpret_cast<const float4*>(p + 4);
    float xs[8] = {x0.x, x0.y, x0.z, x0.w, x1.x, x1.y, x1.z, x1.w};
    union { unsigned int w[4]; bh8 v; } H, L;
    #pragma unroll
    for (int i = 0; i < 4; ++i) {
        const float a = xs[2 * i], b = xs[2 * i + 1];
        unsigned int hw, lw;
        asm("v_cvt_pk_bf16_f32 %0, %1, %2" : "=v"(hw) : "v"(a), "v"(b));
        const float ha = __uint_as_float(hw << 16);
        const float hb = __uint_as_float(hw & 0xFFFF0000u);
        const float la = a - ha, lb = b - hb;
        asm("v_cvt_pk_bf16_f32 %0, %1, %2" : "=v"(lw) : "v"(la), "v"(lb));
        H.w[i] = hw; L.w[i] = lw;
    }
    hi = H.v; lo = L.v;
}

// ---- wprep: split all weights into hi/lo bf16 planes in ws ----
__global__ __launch_bounds__(512) void wprep(
    const float* __restrict__ At_w, const float* __restrict__ Ac_w,
    const float* __restrict__ Bc_w, const float* __restrict__ R_w,
    unsigned short* __restrict__ ws)
{
    const int u = blockIdx.x * 512 + threadIdx.x;     // 16384 units of 8 elems
    bh8 h8, l8;
    if (u < 12288) {                                  // proj: [3][256][128]
        const int p = u >> 12, rem = u & 4095;
        const int col = rem >> 4, e0 = (rem & 15) << 3;
        const float* W = (p == 0) ? At_w : (p == 1) ? Ac_w : Bc_w;
        split8(W + (size_t)col * 128 + e0, h8, l8);
        const size_t o = ((size_t)p * 256 + col) * 128 + e0;
        *reinterpret_cast<bh8*>(ws + o) = h8;
        *reinterpret_cast<bh8*>(ws + WS_PROJ_LO + o) = l8;
    } else {                                          // R: [128][256]
        const int u2 = u - 12288;
        const int e = u2 >> 5, k0 = (u2 & 31) << 3;
        split8(R_w + (size_t)e * 256 + k0, h8, l8);
        const size_t o = (size_t)e * 256 + k0;
        *reinterpret_cast<bh8*>(ws + WS_R_HI + o) = h8;
        *reinterpret_cast<bh8*>(ws + WS_R_LO + o) = l8;
    }
}

// ---- projn: flattened. block = (b, ty, mt); wave = head. ----
// Stage X tile (16 rows x 128 f32, contiguous 8KB) coalesced into LDS; each
// wave: 8 B-frag loads (L2-hot plane) + 8 LDS reads -> cvt -> 8 MFMA ->
// in-register row-norm (q/k only) -> bf16 write.
__global__ __launch_bounds__(512, 6) void projn(
    const float* __restrict__ gq, const float* __restrict__ gk,
    const float* __restrict__ gv,
    const float* __restrict__ At_b, const float* __restrict__ Ac_b,
    const float* __restrict__ Bc_b,
    const unsigned short* __restrict__ wsp,
    unsigned short* __restrict__ qh, unsigned short* __restrict__ kh,
    unsigned short* __restrict__ vh)
{
    __shared__ __align__(16) float sX[16][132];       // 528B row stride

    const int blk = blockIdx.x;
    const int b = blk / 30;
    const int r = blk - b * 30;                       // 0..29
    const int ty = (r < 4) ? 0 : (r < 17) ? 1 : 2;
    const int mt = r - ((ty == 0) ? 0 : (ty == 1) ? 4 : 17);
    const int nrows = (ty == 0) ? NT : NC;
    const float* X = ((ty == 0) ? gq : (ty == 1) ? gk : gv)
                     + (size_t)b * nrows * EMB;
    const float* Bv = (ty == 0) ? At_b : (ty == 1) ? Ac_b : Bc_b;
    unsigned short* O = (ty == 0) ? qh + (size_t)b * (NT * 256)
                      : (ty == 1) ? kh + (size_t)b * (NC * 256)
                                  : vh + (size_t)b * (NC * 256);
    const unsigned short* Wp = wsp + (size_t)ty * 32768;

    const int t = threadIdx.x;
    const int lane = t & 63, head = t >> 6, l15 = lane & 15, g = lane >> 4;
    const int c0i = head * 32 + l15, c1i = c0i + 16;

    // stage X tile: 512 lanes x 16B, rows contiguous (clamped at tile edge)
    {
        int row = mt * 16 + (t >> 5);
        if (row > nrows - 1) row = nrows - 1;
        const float4 xv = *reinterpret_cast<const float4*>(
            X + (size_t)row * EMB + (t & 31) * 4);
        *reinterpret_cast<float4*>(&sX[t >> 5][(t & 31) * 4]) = xv;
    }

    // B fragments + bias (independent of LDS; L2-hot)
    bh8 bf0[4], bf1[4];
    #pragma unroll
    for (int ks = 0; ks < 4; ++ks) {
        bf0[ks] = *reinterpret_cast<const bh8*>(Wp + (size_t)c0i * 128 + ks * 32 + (g << 3));
        bf1[ks] = *reinterpret_cast<const bh8*>(Wp + (size_t)c1i * 128 + ks * 32 + (g << 3));
    }
    const float bias0 = Bv[c0i], bias1 = Bv[c1i];
    __syncthreads();

    f4acc a0 = {bias0, bias0, bias0, bias0};
    f4acc a1 = {bias1, bias1, bias1, bias1};
    #pragma unroll
    for (int ks = 0; ks < 4; ++ks) {
        const bh8 xv = cvt8(&sX[l15][ks * 32 + (g << 3)]);
        a0 = mfma_bf16(xv, bf0[ks], a0);
        a1 = mfma_bf16(xv, bf1[ks], a1);
    }

    if (ty < 2) {                                     // normalize q/k rows
        float s[4];
        #pragma unroll
        for (int rr = 0; rr < 4; ++rr) s[rr] = a0[rr] * a0[rr] + a1[rr] * a1[rr];
        #pragma unroll
        for (int rr = 0; rr < 4; ++rr) {
            s[rr] += __shfl_xor(s[rr], 1);
            s[rr] += __shfl_xor(s[rr], 2);
            s[rr] += __shfl_xor(s[rr], 4);
            s[rr] += __shfl_xor(s[rr], 8);
        }
        #pragma unroll
        for (int rr = 0; rr < 4; ++rr) {
            const float rs = rsqrtf(fmaxf(s[rr], 1e-12f));
            a0[rr] *= rs; a1[rr] *= rs;
        }
    }
    #pragma unroll
    for (int rr = 0; rr < 4; ++rr) {
        const int row = mt * 16 + (g << 2) + rr;
        if (row < nrows) {
            O[(size_t)row * 256 + c0i] = bf16rne(a0[rr]);
            O[(size_t)row * 256 + c1i] = bf16rne(a1[rr]);
        }
    }
}

// ---- attn2: scores + softmax + att + PV + cat, from prestaged bf16 ----
__global__ __launch_bounds__(512, 6) void attn2(
    const unsigned short* __restrict__ qh, const unsigned short* __restrict__ kh,
    const unsigned short* __restrict__ vh, const float* __restrict__ pos_bias,
    float* __restrict__ att, float* __restrict__ cat, int nbat)
{
    const int t = threadIdx.x;
    const int p = blockIdx.x;
    const int chunk = (nbat * NH) >> 3;
    const int lj = (p & 7) * chunk + (p >> 3);
    const int b = lj >> 3, h = lj & 7;
    const int lane = t & 63, wave = t >> 6, l15 = lane & 15, g = lane >> 4;

    __shared__ __align__(16) unsigned char smem[39872];
    unsigned short* sVT = reinterpret_cast<unsigned short*>(smem);
    unsigned short* sK  = reinterpret_cast<unsigned short*>(smem + 14848);
    unsigned short* sQ  = reinterpret_cast<unsigned short*>(smem + 30848);
    unsigned short* sP  = reinterpret_cast<unsigned short*>(smem + 14848);
    float* spb = reinterpret_cast<float*>(smem + 38048);
    float* sSm = reinterpret_cast<float*>(smem + 39360);

    if (t < 448) {
        unsigned int* v32 = reinterpret_cast<unsigned int*>(sVT);
        const int col = t / 14, i = t - col * 14;
        v32[col * 116 + 100 + i] = 0u;
    }
    if (t < NC) spb[t] = pos_bias[t] * LOG2E;
    if (t < 200) {
        const int row = t >> 2, q = t & 3;
        *reinterpret_cast<bh8*>(sQ + row * 40 + q * 8) =
            *reinterpret_cast<const bh8*>(qh + (size_t)b * (NT * 256) + row * 256 + h * 32 + q * 8);
    }
    for (int u = t; u < 800; u += THREADS) {
        const int row = u >> 2, q = u & 3;
        *reinterpret_cast<bh8*>(sK + row * 40 + q * 8) =
            *reinterpret_cast<const bh8*>(kh + (size_t)b * (NC * 256) + row * 256 + h * 32 + q * 8);
    }
    for (int u = t; u < 800; u += THREADS) {
        const int row = u >> 2, q = u & 3;
        const bh8 vv = *reinterpret_cast<const bh8*>(
            vh + (size_t)b * (NC * 256) + row * 256 + h * 32 + q * 8);
        #pragma unroll
        for (int e = 0; e < 8; ++e)
            sVT[(q * 8 + e) * 232 + row] = (unsigned short)vv[e];
    }
    __syncthreads();

    const int mt = wave & 3, hf = wave >> 2;
    const int m0 = mt << 4;
    const int row64 = m0 + (g << 2);
    int arow = m0 + l15; if (arow > NT - 1) arow = NT - 1;
    const bh8 aq = *reinterpret_cast<const bh8*>(sQ + arow * 40 + (g << 3));

    f4acc acc[7];
    #pragma unroll
    for (int i = 0; i < 7; ++i) {
        const int nt = hf * 7 + i;
        if (nt < 13) {
            const int col = (nt << 4) + l15;
            const int bc = (col < NC) ? col : (NC - 1);
            const bh8 bk = *reinterpret_cast<const bh8*>(sK + bc * 40 + (g << 3));
            f4acc c = {0.f, 0.f, 0.f, 0.f};
            c = mfma_bf16(aq, bk, c);
            const float pbl = spb[bc];
            #pragma unroll
            for (int r = 0; r < 4; ++r)
                acc[i][r] = (col < NC) ? fmaf(c[r], LOG2E, pbl) : -1e30f;
        }
    }
    __syncthreads();

    {
        unsigned int* p32 = reinterpret_cast<unsigned int*>(sP);
        for (int tt = t; tt < 700; tt += THREADS) {
            const int row = tt / 14, i = tt - row * 14;
            p32[row * 116 + 100 + i] = 0u;
        }
    }
    {
        float sl[4] = {0.f, 0.f, 0.f, 0.f};
        #pragma unroll
        for (int i = 0; i < 7; ++i) {
            if (hf * 7 + i < 13) {
                #pragma unroll
                for (int r = 0; r < 4; ++r) {
                    const float e = __builtin_exp2f(acc[i][r]);
                    acc[i][r] = e;
                    sl[r] += e;
                }
            }
        }
        #pragma unroll
        for (int r = 0; r < 4; ++r) {
            sl[r] += __shfl_xor(sl[r], 1);
            sl[r] += __shfl_xor(sl[r], 2);
            sl[r] += __shfl_xor(sl[r], 4);
            sl[r] += __shfl_xor(sl[r], 8);
        }
        if (l15 == 0) {
            #pragma unroll
            for (int r = 0; r < 4; ++r) sSm[hf * 64 + row64 + r] = sl[r];
        }
    }
    __syncthreads();

    {
        float inv[4];
        #pragma unroll
        for (int r = 0; r < 4; ++r)
            inv[r] = 1.0f / (sSm[row64 + r] + sSm[64 + row64 + r]);
        float* attb = att + (size_t)(b * NH + h) * NT * NC;
        #pragma unroll
        for (int i = 0; i < 7; ++i) {
            const int nt = hf * 7 + i;
            if (nt < 13) {
                const int col = (nt << 4) + l15;
                if (col < NC) {
                    #pragma unroll
                    for (int r = 0; r < 4; ++r) {
                        const int row = row64 + r;
                        if (row < NT) {
                            const float v = acc[i][r] * inv[r];
                            attb[row * NC + col] = v;
                            sP[row * 232 + col] = bf16rne(v);
                        }
                    }
                }
            }
        }
    }
    __syncthreads();

    {
        const int pnt = wave >> 2;
        const unsigned short* pA = sP + arow * 232;
        const unsigned short* pB = sVT + (size_t)((pnt << 4) + l15) * 232;
        f4acc o = {0.f, 0.f, 0.f, 0.f};
        #pragma unroll
        for (int ks = 0; ks < 7; ++ks) {
            const bh8 a = *reinterpret_cast<const bh8*>(pA + ks * 32 + (g << 3));
            const bh8 v = *reinterpret_cast<const bh8*>(pB + ks * 32 + (g << 3));
            o = mfma_bf16(a, v, o);
        }
        float* wsb = cat + (size_t)b * (NT * NH * DH) + h * DH;
        #pragma unroll
        for (int r = 0; r < 4; ++r) {
            const int row = row64 + r;
            if (row < NT) wsb[(size_t)row * (NH * DH) + (pnt << 4) + l15] = o[r];
        }
    }
}

// ================= round-8 kernel retained as tier-2/3 fallback =============
template <int WSP>
__global__ __launch_bounds__(THREADS, 4) void attn_mfma(
    const float* __restrict__ gq, const float* __restrict__ gk,
    const float* __restrict__ gv,
    const float* __restrict__ At_w, const float* __restrict__ At_b,
    const float* __restrict__ Ac_w, const float* __restrict__ Ac_b,
    const float* __restrict__ Bc_w, const float* __restrict__ Bc_b,
    const float* __restrict__ pos_bias,
    const float* __restrict__ R_w, const float* __restrict__ R_b,
    float* __restrict__ out, float* __restrict__ att,
    float* __restrict__ cat, const unsigned short* __restrict__ wsp,
    int nbat)
{
    const int t = threadIdx.x;
    const int p = blockIdx.x;
    const int chunk = (nbat * NH) >> 3;
    const int lj = (p & 7) * chunk + (p >> 3);
    const int b = lj >> 3;
    const int h = lj & 7;
    const int lane = t & 63, wave = t >> 6;
    const int l15 = lane & 15, g = lane >> 4;

    __shared__ __align__(16) unsigned char smem[39872];
    unsigned short* sVT = reinterpret_cast<unsigned short*>(smem);
    unsigned short* sK  = reinterpret_cast<unsigned short*>(smem + 14848);
    unsigned short* sQ  = reinterpret_cast<unsigned short*>(smem + 30848);
    unsigned short* sP  = reinterpret_cast<unsigned short*>(smem + 14848);
    float* spb = reinterpret_cast<float*>(smem + 38048);
    float* sSm = reinterpret_cast<float*>(smem + 39360);

    if (t < 448) {
        unsigned int* v32 = reinterpret_cast<unsigned int*>(sVT);
        const int col = t / 14, i = t - col * 14;
        v32[col * 116 + 100 + i] = 0u;
    }
    if (t < NC) spb[t] = pos_bias[t] * LOG2E;

    {
        const int s0 = (wave * 60) >> 3;
        const int s1 = ((wave + 1) * 60) >> 3;
        int cp = -1, cn = -1;
        bh8 wh[4], wl[4];
        float bias = 0.f;
        for (int id = s0; id < s1; ++id) {
            int pidx, nt, mt2;
            if (id < 8)       { pidx = 0; nt = id >> 2; mt2 = id & 3; }
            else if (id < 34) { int j = id - 8;  pidx = 1; nt = j / 13; mt2 = j - nt * 13; }
            else              { int j = id - 34; pidx = 2; nt = j / 13; mt2 = j - nt * 13; }
            const int col = (nt << 4) + l15;
            if (pidx != cp || nt != cn) {
                cp = pidx; cn = nt;
                const int gcol = h * DH + col;
                if (WSP) {
                    const unsigned short* whp =
                        wsp + ((size_t)pidx * 256 + gcol) * 128 + (g << 3);
                    const unsigned short* wlp = whp + WS_PROJ_LO;
                    #pragma unroll
                    for (int ks = 0; ks < 4; ++ks) {
                        wh[ks] = *reinterpret_cast<const bh8*>(whp + ks * 32);
                        wl[ks] = *reinterpret_cast<const bh8*>(wlp + ks * 32);
                    }
                } else {
                    const float* Wm = (pidx == 0) ? At_w : (pidx == 1) ? Ac_w : Bc_w;
                    const float* bp = Wm + (size_t)gcol * EMB + (g << 3);
                    #pragma unroll
                    for (int ks = 0; ks < 4; ++ks) split8(bp + ks * 32, wh[ks], wl[ks]);
                }
                const float* Wb = (pidx == 0) ? At_b : (pidx == 1) ? Ac_b : Bc_b;
                bias = Wb[gcol];
            }
            const int nrows = (pidx == 0) ? NT : NC;
            const float* Xb = (pidx == 0) ? gq : (pidx == 1) ? gk : gv;
            int ar = mt2 * 16 + l15; if (ar > nrows - 1) ar = nrows - 1;
            const float* ap = Xb + (size_t)b * nrows * EMB + (size_t)ar * EMB + (g << 3);
            f4acc acc2 = {bias, bias, bias, bias};
            #pragma unroll
            for (int ks = 0; ks < 4; ++ks) {
                bh8 xh, xl;
                split8(ap + ks * 32, xh, xl);
                acc2 = mfma_bf16(xh, wh[ks], acc2);
                acc2 = mfma_bf16(xl, wh[ks], acc2);
                acc2 = mfma_bf16(xh, wl[ks], acc2);
            }
            #pragma unroll
            for (int r = 0; r < 4; ++r) {
                const int row = mt2 * 16 + (g << 2) + r;
                if (row < nrows) {
                    const unsigned short hv = bf16rne(acc2[r]);
                    if (pidx == 0)      sQ[row * 40 + col] = hv;
                    else if (pidx == 1) sK[row * 40 + col] = hv;
                    else                sVT[col * 232 + row] = hv;
                }
            }
        }
    }
    __syncthreads();

    if (t < 250) {
        unsigned short* rowp = (t < 200) ? (sK + t * 40) : (sQ + (t - 200) * 40);
        unsigned int* w32 = reinterpret_cast<unsigned int*>(rowp);
        unsigned int w[16];
        #pragma unroll
        for (int i = 0; i < 16; ++i) w[i] = w32[i];
        float s = 0.f;
        #pragma unroll
        for (int i = 0; i < 16; ++i) {
            const float a = __uint_as_float(w[i] << 16);
            const float c = __uint_as_float(w[i] & 0xFFFF0000u);
            s += a * a + c * c;
        }
        const float rs = rsqrtf(fmaxf(s, 1e-12f));
        #pragma unroll
        for (int i = 0; i < 16; ++i) {
            const float a = __uint_as_float(w[i] << 16) * rs;
            const float c = __uint_as_float(w[i] & 0xFFFF0000u) * rs;
            unsigned int pw;
            asm("v_cvt_pk_bf16_f32 %0, %1, %2" : "=v"(pw) : "v"(a), "v"(c));
            w32[i] = pw;
        }
    }
    __syncthreads();

    const int mt = wave & 3, hf = wave >> 2;
    const int m0 = mt << 4;
    const int row64 = m0 + (g << 2);
    int arow = m0 + l15; if (arow > NT - 1) arow = NT - 1;
    const bh8 aq = *reinterpret_cast<const bh8*>(sQ + arow * 40 + (g << 3));

    f4acc acc[7];
    #pragma unroll
    for (int i = 0; i < 7; ++i) {
        const int nt = hf * 7 + i;
        if (nt < 13) {
            const int col = (nt << 4) + l15;
            const int bc = (col < NC) ? col : (NC - 1);
            const bh8 bk = *reinterpret_cast<const bh8*>(sK + bc * 40 + (g << 3));
            f4acc c = {0.f, 0.f, 0.f, 0.f};
            c = mfma_bf16(aq, bk, c);
            const float pbl = spb[bc];
            #pragma unroll
            for (int r = 0; r < 4; ++r)
                acc[i][r] = (col < NC) ? fmaf(c[r], LOG2E, pbl) : -1e30f;
        }
    }
    __syncthreads();

    {
        unsigned int* p32 = reinterpret_cast<unsigned int*>(sP);
        for (int tt = t; tt < 700; tt += THREADS) {
            const int row = tt / 14, i = tt - row * 14;
            p32[row * 116 + 100 + i] = 0u;
        }
    }
    {
        float sl[4] = {0.f, 0.f, 0.f, 0.f};
        #pragma unroll
        for (int i = 0; i < 7; ++i) {
            if (hf * 7 + i < 13) {
                #pragma unroll
                for (int r = 0; r < 4; ++r) {
                    const float e = __builtin_exp2f(acc[i][r]);
                    acc[i][r] = e;
                    sl[r] += e;
                }
            }
        }
        #pragma unroll
        for (int r = 0; r < 4; ++r) {
            sl[r] += __shfl_xor(sl[r], 1);
            sl[r] += __shfl_xor(sl[r], 2);
            sl[r] += __shfl_xor(sl[r], 4);
            sl[r] += __shfl_xor(sl[r], 8);
        }
        if (l15 == 0) {
            #pragma unroll
            for (int r = 0; r < 4; ++r) sSm[hf * 64 + row64 + r] = sl[r];
        }
    }
    __syncthreads();

    {
        float inv[4];
        #pragma unroll
        for (int r = 0; r < 4; ++r)
            inv[r] = 1.0f / (sSm[row64 + r] + sSm[64 + row64 + r]);
        float* attb = att + (size_t)(b * NH + h) * NT * NC;
        #pragma unroll
        for (int i = 0; i < 7; ++i) {
            const int nt = hf * 7 + i;
            if (nt < 13) {
                const int col = (nt << 4) + l15;
                if (col < NC) {
                    #pragma unroll
                    for (int r = 0; r < 4; ++r) {
                        const int row = row64 + r;
                        if (row < NT) {
                            const float v = acc[i][r] * inv[r];
                            attb[row * NC + col] = v;
                            sP[row * 232 + col] = bf16rne(v);
                        }
                    }
                }
            }
        }
    }
    __syncthreads();

    {
        const int pnt = wave >> 2;
        const unsigned short* pA = sP + arow * 232;
        const unsigned short* pB = sVT + (size_t)((pnt << 4) + l15) * 232;
        f4acc o = {0.f, 0.f, 0.f, 0.f};
        #pragma unroll
        for (int ks = 0; ks < 7; ++ks) {
            const bh8 a = *reinterpret_cast<const bh8*>(pA + ks * 32 + (g << 3));
            const bh8 v = *reinterpret_cast<const bh8*>(pB + ks * 32 + (g << 3));
            o = mfma_bf16(a, v, o);
        }
        if (WSP) {
            float* wsb = cat + (size_t)b * (NT * NH * DH) + h * DH;
            #pragma unroll
            for (int r = 0; r < 4; ++r) {
                const int row = row64 + r;
                if (row < NT) wsb[(size_t)row * (NH * DH) + (pnt << 4) + l15] = o[r];
            }
        } else {
            __syncthreads();
            float* sOH = reinterpret_cast<float*>(smem);
            #pragma unroll
            for (int r = 0; r < 4; ++r) {
                const int row = row64 + r;
                if (row < NT) sOH[row * DH + (pnt << 4) + l15] = o[r];
            }
            __syncthreads();
            for (int oo = t; oo < NT * EMB; oo += THREADS) {
                const int r = oo >> 7, e = oo & 127;
                float s = (h == 0) ? R_b[e] : 0.f;
                const float* rw = R_w + (size_t)e * (NH * DH) + h * DH;
                const float* oh = sOH + r * DH;
                #pragma unroll
                for (int c = 0; c < DH; ++c) s += oh[c] * rw[c];
                atomicAdd(&out[((size_t)b * NT + r) * EMB + e], s);
            }
        }
    }
}

// rproj4: MFMA GEMM. out[51200x128] = cat[51200x256] @ R_w[128x256]^T + R_b.
__global__ __launch_bounds__(256, 4) void rproj4(
    const float* __restrict__ cat, const unsigned short* __restrict__ rhi,
    const float* __restrict__ R_b, float* __restrict__ out)
{
    const int t = threadIdx.x;
    const int lane = t & 63, wave = t >> 6;
    const int l15 = lane & 15, g = lane >> 4;
    const int m0 = blockIdx.x * 64 + wave * 16;
    const float* ap = cat + (size_t)(m0 + l15) * 256 + (g << 3);
    const unsigned short* rlo = rhi + (WS_R_LO - WS_R_HI);

    f4acc acc[8];
    #pragma unroll
    for (int nt = 0; nt < 8; ++nt) {
        const float rb = R_b[nt * 16 + l15];
        acc[nt][0] = rb; acc[nt][1] = rb; acc[nt][2] = rb; acc[nt][3] = rb;
    }
    #pragma unroll
    for (int ks = 0; ks < 8; ++ks) {
        bh8 ah, al;
        split8(ap + ks * 32, ah, al);
        #pragma unroll
        for (int nt = 0; nt < 8; ++nt) {
            const size_t o = (size_t)(nt * 16 + l15) * 256 + ks * 32 + (g << 3);
            const bh8 bh_ = *reinterpret_cast<const bh8*>(rhi + o);
            const bh8 bl_ = *reinterpret_cast<const bh8*>(rlo + o);
            acc[nt] = mfma_bf16(ah, bh_, acc[nt]);
            acc[nt] = mfma_bf16(al, bh_, acc[nt]);
            acc[nt] = mfma_bf16(ah, bl_, acc[nt]);
        }
    }
    const int row = m0 + (g << 2);
    #pragma unroll
    for (int nt = 0; nt < 8; ++nt) {
        #pragma unroll
        for (int r = 0; r < 4; ++r)
            out[(size_t)(row + r) * EMB + nt * 16 + l15] = acc[nt][r];
    }
}

extern "C" void kernel_launch(void* const* d_in, const int* in_sizes, int n_in,
                              void* d_out, int out_size, void* d_ws, size_t ws_size,
                              hipStream_t stream)
{
    const float* gq   = (const float*)d_in[0];
    const float* gk   = (const float*)d_in[1];
    const float* gv   = (const float*)d_in[2];
    const float* At_w = (const float*)d_in[3];
    const float* At_b = (const float*)d_in[4];
    const float* Ac_w = (const float*)d_in[5];
    const float* Ac_b = (const float*)d_in[6];
    const float* Bc_w = (const float*)d_in[7];
    const float* Bc_b = (const float*)d_in[8];
    const float* pb   = (const float*)d_in[9];
    const float* R_w  = (const float*)d_in[10];
    const float* R_b  = (const float*)d_in[11];

    const int nbat = in_sizes[0] / (NT * EMB);   // 1024
    float* out = (float*)d_out;
    float* att = out + (size_t)nbat * NT * EMB;

    const size_t qB   = (size_t)nbat * NT * 256 * 2;
    const size_t kB   = (size_t)nbat * NC * 256 * 2;
    const size_t catB = (size_t)nbat * NT * NH * DH * sizeof(float);
    const size_t need3 = WS_PLANES_B + qB + 2 * kB + catB;   // ~289 MB
    const size_t need2 = WS_PLANES_B + catB;                 // ~53 MB
    const int nwg = nbat * NH;

    if (ws_size >= need3) {
        unsigned short* wsp = (unsigned short*)d_ws;
        unsigned short* qh = (unsigned short*)((char*)d_ws + WS_PLANES_B);
        unsigned short* kh = (unsigned short*)((char*)d_ws + WS_PLANES_B + qB);
        unsigned short* vh = (unsigned short*)((char*)d_ws + WS_PLANES_B + qB + kB);
        float* cat = (float*)((char*)d_ws + WS_PLANES_B + qB + 2 * kB);
        wprep<<<32, 512, 0, stream>>>(At_w, Ac_w, Bc_w, R_w, wsp);
        projn<<<nbat * 30, 512, 0, stream>>>(gq, gk, gv, At_b, Ac_b, Bc_b,
                                             wsp, qh, kh, vh);
        attn2<<<nwg, THREADS, 0, stream>>>(qh, kh, vh, pb, att, cat, nbat);
        rproj4<<<(nbat * NT) / 64, 256, 0, stream>>>(cat, wsp + WS_R_HI, R_b, out);
    } else if (ws_size >= need2) {
        unsigned short* wsp = (unsigned short*)d_ws;
        float* cat = (float*)((char*)d_ws + WS_PLANES_B);
        wprep<<<32, 512, 0, stream>>>(At_w, Ac_w, Bc_w, R_w, wsp);
        attn_mfma<1><<<nwg, THREADS, 0, stream>>>(
            gq, gk, gv, At_w, At_b, Ac_w, Ac_b, Bc_w, Bc_b, pb, R_w, R_b,
            out, att, cat, wsp, nbat);
        rproj4<<<(nbat * NT) / 64, 256, 0, stream>>>(cat, wsp + WS_R_HI, R_b, out);
    } else {
        hipMemsetAsync(d_out, 0, (size_t)nbat * NT * EMB * sizeof(float), stream);
        attn_mfma<0><<<nwg, THREADS, 0, stream>>>(
            gq, gk, gv, At_w, At_b, Ac_w, Ac_b, Bc_w, Bc_b, pb, R_w, R_b,
            out, att, nullptr, nullptr, nbat);
    }
}

// Round 11
// 369.152 us; speedup vs baseline: 2.0334x; 1.4426x over previous
//
#include <hip/hip_runtime.h>

// ---------------------------------------------------------------------------
// Cosine-similarity MHA, round 11:
//  projn v3: fragment-major swizzled W planes (1KB contiguous frag loads,
//    16 lines/instr vs 64), 2 tiles/block (W loaded once), reg-prefetched X,
//    coalesced bf16 output flush via LDS staging.
//  attn2 / rproj4: unchanged.
// ws shorts: [0,98304) proj hi; [98304,196608) proj lo; [196608,229376) R hi;
//   [229376,262144) R lo; [262144,360448) proj hi SWIZZLED. Then qh/kh/vh/cat.
// ---------------------------------------------------------------------------

#define NT 50
#define NC 200
#define EMB 128
#define DH 32
#define NH 8
#define THREADS 512
#define LOG2E 1.44269504088896340736f

#define WS_PROJ_LO 98304u       // short offset of proj lo plane
#define WS_R_HI    196608u      // short offset of R hi plane
#define WS_R_LO    229376u      // short offset of R lo plane
#define WS_PSW     262144u      // short offset of swizzled proj hi plane
#define WS_PLANES_B 720896u     // bytes: end of weight planes (incl swizzled)

typedef __attribute__((ext_vector_type(4))) float f4acc;
typedef __attribute__((ext_vector_type(8))) short bh8;

__device__ __forceinline__ f4acc mfma_bf16(bh8 a, bh8 b, f4acc c) {
    return __builtin_amdgcn_mfma_f32_16x16x32_bf16(a, b, c, 0, 0, 0);
}

__device__ __forceinline__ unsigned short bf16rne(float x) {
    unsigned int u = __float_as_uint(x);
    u += 0x7FFFu + ((u >> 16) & 1u);
    return (unsigned short)(u >> 16);
}

// 8 f32 -> bf16 RNE (packed); pair order identical for A and B operands.
__device__ __forceinline__ bh8 cvt8(const float* __restrict__ p) {
    float4 x0 = *reinterpret_cast<const float4*>(p);
    float4 x1 = *reinterpret_cast<const float4*>(p + 4);
    float xs[8] = {x0.x, x0.y, x0.z, x0.w, x1.x, x1.y, x1.z, x1.w};
    union { unsigned int w[4]; bh8 v; } H;
    #pragma unroll
    for (int i = 0; i < 4; ++i)
        asm("v_cvt_pk_bf16_f32 %0, %1, %2"
            : "=v"(H.w[i]) : "v"(xs[2 * i]), "v"(xs[2 * i + 1]));
    return H.v;
}

__device__ __forceinline__ void split8(const float* __restrict__ p, bh8& hi, bh8& lo) {
    float4 x0 = *reinterpret_cast<const float4*>(p);
    float4 x1 = *reinterpret_cast<const float4*>(p + 4);
    float xs[8] = {x0.x, x0.y, x0.z, x0.w, x1.x, x1.y, x1.z, x1.w};
    union { unsigned int w[4]; bh8 v; } H, L;
    #pragma unroll
    for (int i = 0; i < 4; ++i) {
        const float a = xs[2 * i], b = xs[2 * i + 1];
        unsigned int hw, lw;
        asm("v_cvt_pk_bf16_f32 %0, %1, %2" : "=v"(hw) : "v"(a), "v"(b));
        const float ha = __uint_as_float(hw << 16);
        const float hb = __uint_as_float(hw & 0xFFFF0000u);
        const float la = a - ha, lb = b - hb;
        asm("v_cvt_pk_bf16_f32 %0, %1, %2" : "=v"(lw) : "v"(la), "v"(lb));
        H.w[i] = hw; L.w[i] = lw;
    }
    hi = H.v; lo = L.v;
}

// ---- wprep: linear hi/lo planes + R planes + fragment-major swizzled plane --
__global__ __launch_bounds__(512) void wprep(
    const float* __restrict__ At_w, const float* __restrict__ Ac_w,
    const float* __restrict__ Bc_w, const float* __restrict__ R_w,
    unsigned short* __restrict__ ws)
{
    const int u = blockIdx.x * 512 + threadIdx.x;     // 28672 units of 8 elems
    bh8 h8, l8;
    if (u < 12288) {                                  // proj: [3][256][128]
        const int p = u >> 12, rem = u & 4095;
        const int col = rem >> 4, e0 = (rem & 15) << 3;
        const float* W = (p == 0) ? At_w : (p == 1) ? Ac_w : Bc_w;
        split8(W + (size_t)col * 128 + e0, h8, l8);
        const size_t o = ((size_t)p * 256 + col) * 128 + e0;
        *reinterpret_cast<bh8*>(ws + o) = h8;
        *reinterpret_cast<bh8*>(ws + WS_PROJ_LO + o) = l8;
    } else if (u < 16384) {                           // R: [128][256]
        const int u2 = u - 12288;
        const int e = u2 >> 5, k0 = (u2 & 31) << 3;
        split8(R_w + (size_t)e * 256 + k0, h8, l8);
        const size_t o = (size_t)e * 256 + k0;
        *reinterpret_cast<bh8*>(ws + WS_R_HI + o) = h8;
        *reinterpret_cast<bh8*>(ws + WS_R_LO + o) = l8;
    } else {                                          // swizzled proj hi
        const int u2 = u - 16384;                     // 12288 units
        const int lane = u2 & 63;
        const int ks = (u2 >> 6) & 3;
        const int colgrp = (u2 >> 8) & 1;
        const int head = (u2 >> 9) & 7;
        const int ty = u2 >> 12;
        const float* W = (ty == 0) ? At_w : (ty == 1) ? Ac_w : Bc_w;
        const int col = head * 32 + colgrp * 16 + (lane & 15);
        const int g = lane >> 4;
        *reinterpret_cast<bh8*>(ws + WS_PSW + (size_t)u2 * 8) =
            cvt8(W + (size_t)col * 128 + ks * 32 + g * 8);
    }
}

// ---- projn v3 ----
// block = (batch, pair j of tiles r=2j,2j+1), r: 0..3 q, 4..16 k, 17..29 v.
// Wave = head. W frags: 1KB contiguous loads from swizzled plane, loaded once
// (reloaded only for the single k/v straddle pair). X reg-prefetched; output
// staged bf16 in sO, flushed coalesced (512 x 16B).
__device__ __forceinline__ void projn_wfrag(
    const unsigned short* __restrict__ wsp, int ty, int head, int lane,
    bh8* bf0, bh8* bf1)
{
    const unsigned short* base = wsp + WS_PSW + ((size_t)(ty * 8 + head) << 12)
                               + (size_t)lane * 8;
    #pragma unroll
    for (int ks = 0; ks < 4; ++ks) {
        bf0[ks] = *reinterpret_cast<const bh8*>(base + (ks << 9));
        bf1[ks] = *reinterpret_cast<const bh8*>(base + 2048 + (ks << 9));
    }
}

__global__ __launch_bounds__(512, 6) void projn(
    const float* __restrict__ gq, const float* __restrict__ gk,
    const float* __restrict__ gv,
    const float* __restrict__ At_b, const float* __restrict__ Ac_b,
    const float* __restrict__ Bc_b,
    const unsigned short* __restrict__ wsp,
    unsigned short* __restrict__ qh, unsigned short* __restrict__ kh,
    unsigned short* __restrict__ vh)
{
    __shared__ __align__(16) float sX[16][132];
    __shared__ __align__(16) unsigned short sO[16 * 256];

    const int blk = blockIdx.x;
    const int b = blk / 15, j = blk - b * 15;
    const int t = threadIdx.x;
    const int lane = t & 63, head = t >> 6, l15 = lane & 15, g = lane >> 4;
    const int c0i = head * 32 + l15, c1i = c0i + 16;
    const int srow = t >> 5, scol = (t & 31) * 4;     // stage coords

    int ty0, mt0, ty1, mt1;
    {
        const int r0 = 2 * j, r1 = 2 * j + 1;
        ty0 = (r0 < 4) ? 0 : (r0 < 17) ? 1 : 2;
        mt0 = r0 - ((ty0 == 0) ? 0 : (ty0 == 1) ? 4 : 17);
        ty1 = (r1 < 4) ? 0 : (r1 < 17) ? 1 : 2;
        mt1 = r1 - ((ty1 == 0) ? 0 : (ty1 == 1) ? 4 : 17);
    }
    const int nrows0 = (ty0 == 0) ? NT : NC;
    const int nrows1 = (ty1 == 0) ? NT : NC;
    const float* X0 = ((ty0 == 0) ? gq : (ty0 == 1) ? gk : gv) + (size_t)b * nrows0 * EMB;
    const float* X1 = ((ty1 == 0) ? gq : (ty1 == 1) ? gk : gv) + (size_t)b * nrows1 * EMB;
    unsigned short* O0 = ((ty0 == 0) ? qh + (size_t)b * (NT * 256)
                        : (ty0 == 1) ? kh + (size_t)b * (NC * 256)
                                     : vh + (size_t)b * (NC * 256));
    unsigned short* O1 = ((ty1 == 0) ? qh + (size_t)b * (NT * 256)
                        : (ty1 == 1) ? kh + (size_t)b * (NC * 256)
                                     : vh + (size_t)b * (NC * 256));

    // stage tile0 -> LDS; prefetch W frags (tile0 type) meanwhile
    {
        int row = mt0 * 16 + srow; if (row > nrows0 - 1) row = nrows0 - 1;
        *reinterpret_cast<float4*>(&sX[srow][scol]) =
            *reinterpret_cast<const float4*>(X0 + (size_t)row * EMB + scol);
    }
    bh8 bf0[4], bf1[4];
    projn_wfrag(wsp, ty0, head, lane, bf0, bf1);
    const float* Bv0 = (ty0 == 0) ? At_b : (ty0 == 1) ? Ac_b : Bc_b;
    float bias0 = Bv0[c0i], bias1 = Bv0[c1i];
    __syncthreads();

    // prefetch tile1 X into registers (latency hides under tile0 compute)
    float4 xreg;
    {
        int row = mt1 * 16 + srow; if (row > nrows1 - 1) row = nrows1 - 1;
        xreg = *reinterpret_cast<const float4*>(X1 + (size_t)row * EMB + scol);
    }

    // ---- tile 0 compute ----
    {
        f4acc a0 = {bias0, bias0, bias0, bias0};
        f4acc a1 = {bias1, bias1, bias1, bias1};
        #pragma unroll
        for (int ks = 0; ks < 4; ++ks) {
            const bh8 xv = cvt8(&sX[l15][ks * 32 + (g << 3)]);
            a0 = mfma_bf16(xv, bf0[ks], a0);
            a1 = mfma_bf16(xv, bf1[ks], a1);
        }
        if (ty0 < 2) {
            float s[4];
            #pragma unroll
            for (int rr = 0; rr < 4; ++rr) s[rr] = a0[rr] * a0[rr] + a1[rr] * a1[rr];
            #pragma unroll
            for (int rr = 0; rr < 4; ++rr) {
                s[rr] += __shfl_xor(s[rr], 1);
                s[rr] += __shfl_xor(s[rr], 2);
                s[rr] += __shfl_xor(s[rr], 4);
                s[rr] += __shfl_xor(s[rr], 8);
            }
            #pragma unroll
            for (int rr = 0; rr < 4; ++rr) {
                const float rs = rsqrtf(fmaxf(s[rr], 1e-12f));
                a0[rr] *= rs; a1[rr] *= rs;
            }
        }
        #pragma unroll
        for (int rr = 0; rr < 4; ++rr) {
            const int row = (g << 2) + rr;
            sO[row * 256 + c0i] = bf16rne(a0[rr]);
            sO[row * 256 + c1i] = bf16rne(a1[rr]);
        }
    }
    __syncthreads();
    // flush tile0 (coalesced 16B per thread), then overwrite sX with tile1
    {
        const int grow = mt0 * 16 + srow;
        if (grow < nrows0)
            *reinterpret_cast<bh8*>(O0 + (size_t)grow * 256 + (t & 31) * 8) =
                *reinterpret_cast<const bh8*>(&sO[srow * 256 + (t & 31) * 8]);
    }
    __syncthreads();
    *reinterpret_cast<float4*>(&sX[srow][scol]) = xreg;
    if (ty1 != ty0) {                                  // straddle pair only
        projn_wfrag(wsp, ty1, head, lane, bf0, bf1);
        const float* Bv1 = (ty1 == 0) ? At_b : (ty1 == 1) ? Ac_b : Bc_b;
        bias0 = Bv1[c0i]; bias1 = Bv1[c1i];
    }
    __syncthreads();

    // ---- tile 1 compute ----
    {
        f4acc a0 = {bias0, bias0, bias0, bias0};
        f4acc a1 = {bias1, bias1, bias1, bias1};
        #pragma unroll
        for (int ks = 0; ks < 4; ++ks) {
            const bh8 xv = cvt8(&sX[l15][ks * 32 + (g << 3)]);
            a0 = mfma_bf16(xv, bf0[ks], a0);
            a1 = mfma_bf16(xv, bf1[ks], a1);
        }
        if (ty1 < 2) {
            float s[4];
            #pragma unroll
            for (int rr = 0; rr < 4; ++rr) s[rr] = a0[rr] * a0[rr] + a1[rr] * a1[rr];
            #pragma unroll
            for (int rr = 0; rr < 4; ++rr) {
                s[rr] += __shfl_xor(s[rr], 1);
                s[rr] += __shfl_xor(s[rr], 2);
                s[rr] += __shfl_xor(s[rr], 4);
                s[rr] += __shfl_xor(s[rr], 8);
            }
            #pragma unroll
            for (int rr = 0; rr < 4; ++rr) {
                const float rs = rsqrtf(fmaxf(s[rr], 1e-12f));
                a0[rr] *= rs; a1[rr] *= rs;
            }
        }
        #pragma unroll
        for (int rr = 0; rr < 4; ++rr) {
            const int row = (g << 2) + rr;
            sO[row * 256 + c0i] = bf16rne(a0[rr]);
            sO[row * 256 + c1i] = bf16rne(a1[rr]);
        }
    }
    __syncthreads();
    {
        const int grow = mt1 * 16 + srow;
        if (grow < nrows1)
            *reinterpret_cast<bh8*>(O1 + (size_t)grow * 256 + (t & 31) * 8) =
                *reinterpret_cast<const bh8*>(&sO[srow * 256 + (t & 31) * 8]);
    }
}

// ---- attn2: scores + softmax + att + PV + cat, from prestaged bf16 ----
__global__ __launch_bounds__(512, 6) void attn2(
    const unsigned short* __restrict__ qh, const unsigned short* __restrict__ kh,
    const unsigned short* __restrict__ vh, const float* __restrict__ pos_bias,
    float* __restrict__ att, float* __restrict__ cat, int nbat)
{
    const int t = threadIdx.x;
    const int p = blockIdx.x;
    const int chunk = (nbat * NH) >> 3;
    const int lj = (p & 7) * chunk + (p >> 3);
    const int b = lj >> 3, h = lj & 7;
    const int lane = t & 63, wave = t >> 6, l15 = lane & 15, g = lane >> 4;

    __shared__ __align__(16) unsigned char smem[39872];
    unsigned short* sVT = reinterpret_cast<unsigned short*>(smem);
    unsigned short* sK  = reinterpret_cast<unsigned short*>(smem + 14848);
    unsigned short* sQ  = reinterpret_cast<unsigned short*>(smem + 30848);
    unsigned short* sP  = reinterpret_cast<unsigned short*>(smem + 14848);
    float* spb = reinterpret_cast<float*>(smem + 38048);
    float* sSm = reinterpret_cast<float*>(smem + 39360);

    if (t < 448) {
        unsigned int* v32 = reinterpret_cast<unsigned int*>(sVT);
        const int col = t / 14, i = t - col * 14;
        v32[col * 116 + 100 + i] = 0u;
    }
    if (t < NC) spb[t] = pos_bias[t] * LOG2E;
    if (t < 200) {
        const int row = t >> 2, q = t & 3;
        *reinterpret_cast<bh8*>(sQ + row * 40 + q * 8) =
            *reinterpret_cast<const bh8*>(qh + (size_t)b * (NT * 256) + row * 256 + h * 32 + q * 8);
    }
    for (int u = t; u < 800; u += THREADS) {
        const int row = u >> 2, q = u & 3;
        *reinterpret_cast<bh8*>(sK + row * 40 + q * 8) =
            *reinterpret_cast<const bh8*>(kh + (size_t)b * (NC * 256) + row * 256 + h * 32 + q * 8);
    }
    for (int u = t; u < 800; u += THREADS) {
        const int row = u >> 2, q = u & 3;
        const bh8 vv = *reinterpret_cast<const bh8*>(
            vh + (size_t)b * (NC * 256) + row * 256 + h * 32 + q * 8);
        #pragma unroll
        for (int e = 0; e < 8; ++e)
            sVT[(q * 8 + e) * 232 + row] = (unsigned short)vv[e];
    }
    __syncthreads();

    const int mt = wave & 3, hf = wave >> 2;
    const int m0 = mt << 4;
    const int row64 = m0 + (g << 2);
    int arow = m0 + l15; if (arow > NT - 1) arow = NT - 1;
    const bh8 aq = *reinterpret_cast<const bh8*>(sQ + arow * 40 + (g << 3));

    f4acc acc[7];
    #pragma unroll
    for (int i = 0; i < 7; ++i) {
        const int nt = hf * 7 + i;
        if (nt < 13) {
            const int col = (nt << 4) + l15;
            const int bc = (col < NC) ? col : (NC - 1);
            const bh8 bk = *reinterpret_cast<const bh8*>(sK + bc * 40 + (g << 3));
            f4acc c = {0.f, 0.f, 0.f, 0.f};
            c = mfma_bf16(aq, bk, c);
            const float pbl = spb[bc];
            #pragma unroll
            for (int r = 0; r < 4; ++r)
                acc[i][r] = (col < NC) ? fmaf(c[r], LOG2E, pbl) : -1e30f;
        }
    }
    __syncthreads();

    {
        unsigned int* p32 = reinterpret_cast<unsigned int*>(sP);
        for (int tt = t; tt < 700; tt += THREADS) {
            const int row = tt / 14, i = tt - row * 14;
            p32[row * 116 + 100 + i] = 0u;
        }
    }
    {
        float sl[4] = {0.f, 0.f, 0.f, 0.f};
        #pragma unroll
        for (int i = 0; i < 7; ++i) {
            if (hf * 7 + i < 13) {
                #pragma unroll
                for (int r = 0; r < 4; ++r) {
                    const float e = __builtin_exp2f(acc[i][r]);
                    acc[i][r] = e;
                    sl[r] += e;
                }
            }
        }
        #pragma unroll
        for (int r = 0; r < 4; ++r) {
            sl[r] += __shfl_xor(sl[r], 1);
            sl[r] += __shfl_xor(sl[r], 2);
            sl[r] += __shfl_xor(sl[r], 4);
            sl[r] += __shfl_xor(sl[r], 8);
        }
        if (l15 == 0) {
            #pragma unroll
            for (int r = 0; r < 4; ++r) sSm[hf * 64 + row64 + r] = sl[r];
        }
    }
    __syncthreads();

    {
        float inv[4];
        #pragma unroll
        for (int r = 0; r < 4; ++r)
            inv[r] = 1.0f / (sSm[row64 + r] + sSm[64 + row64 + r]);
        float* attb = att + (size_t)(b * NH + h) * NT * NC;
        #pragma unroll
        for (int i = 0; i < 7; ++i) {
            const int nt = hf * 7 + i;
            if (nt < 13) {
                const int col = (nt << 4) + l15;
                if (col < NC) {
                    #pragma unroll
                    for (int r = 0; r < 4; ++r) {
                        const int row = row64 + r;
                        if (row < NT) {
                            const float v = acc[i][r] * inv[r];
                            attb[row * NC + col] = v;
                            sP[row * 232 + col] = bf16rne(v);
                        }
                    }
                }
            }
        }
    }
    __syncthreads();

    {
        const int pnt = wave >> 2;
        const unsigned short* pA = sP + arow * 232;
        const unsigned short* pB = sVT + (size_t)((pnt << 4) + l15) * 232;
        f4acc o = {0.f, 0.f, 0.f, 0.f};
        #pragma unroll
        for (int ks = 0; ks < 7; ++ks) {
            const bh8 a = *reinterpret_cast<const bh8*>(pA + ks * 32 + (g << 3));
            const bh8 v = *reinterpret_cast<const bh8*>(pB + ks * 32 + (g << 3));
            o = mfma_bf16(a, v, o);
        }
        float* wsb = cat + (size_t)b * (NT * NH * DH) + h * DH;
        #pragma unroll
        for (int r = 0; r < 4; ++r) {
            const int row = row64 + r;
            if (row < NT) wsb[(size_t)row * (NH * DH) + (pnt << 4) + l15] = o[r];
        }
    }
}

// ================= round-8 kernel retained as tier-2/3 fallback =============
template <int WSP>
__global__ __launch_bounds__(THREADS, 4) void attn_mfma(
    const float* __restrict__ gq, const float* __restrict__ gk,
    const float* __restrict__ gv,
    const float* __restrict__ At_w, const float* __restrict__ At_b,
    const float* __restrict__ Ac_w, const float* __restrict__ Ac_b,
    const float* __restrict__ Bc_w, const float* __restrict__ Bc_b,
    const float* __restrict__ pos_bias,
    const float* __restrict__ R_w, const float* __restrict__ R_b,
    float* __restrict__ out, float* __restrict__ att,
    float* __restrict__ cat, const unsigned short* __restrict__ wsp,
    int nbat)
{
    const int t = threadIdx.x;
    const int p = blockIdx.x;
    const int chunk = (nbat * NH) >> 3;
    const int lj = (p & 7) * chunk + (p >> 3);
    const int b = lj >> 3;
    const int h = lj & 7;
    const int lane = t & 63, wave = t >> 6;
    const int l15 = lane & 15, g = lane >> 4;

    __shared__ __align__(16) unsigned char smem[39872];
    unsigned short* sVT = reinterpret_cast<unsigned short*>(smem);
    unsigned short* sK  = reinterpret_cast<unsigned short*>(smem + 14848);
    unsigned short* sQ  = reinterpret_cast<unsigned short*>(smem + 30848);
    unsigned short* sP  = reinterpret_cast<unsigned short*>(smem + 14848);
    float* spb = reinterpret_cast<float*>(smem + 38048);
    float* sSm = reinterpret_cast<float*>(smem + 39360);

    if (t < 448) {
        unsigned int* v32 = reinterpret_cast<unsigned int*>(sVT);
        const int col = t / 14, i = t - col * 14;
        v32[col * 116 + 100 + i] = 0u;
    }
    if (t < NC) spb[t] = pos_bias[t] * LOG2E;

    {
        const int s0 = (wave * 60) >> 3;
        const int s1 = ((wave + 1) * 60) >> 3;
        int cp = -1, cn = -1;
        bh8 wh[4], wl[4];
        float bias = 0.f;
        for (int id = s0; id < s1; ++id) {
            int pidx, nt, mt2;
            if (id < 8)       { pidx = 0; nt = id >> 2; mt2 = id & 3; }
            else if (id < 34) { int jj = id - 8;  pidx = 1; nt = jj / 13; mt2 = jj - nt * 13; }
            else              { int jj = id - 34; pidx = 2; nt = jj / 13; mt2 = jj - nt * 13; }
            const int col = (nt << 4) + l15;
            if (pidx != cp || nt != cn) {
                cp = pidx; cn = nt;
                const int gcol = h * DH + col;
                if (WSP) {
                    const unsigned short* whp =
                        wsp + ((size_t)pidx * 256 + gcol) * 128 + (g << 3);
                    const unsigned short* wlp = whp + WS_PROJ_LO;
                    #pragma unroll
                    for (int ks = 0; ks < 4; ++ks) {
                        wh[ks] = *reinterpret_cast<const bh8*>(whp + ks * 32);
                        wl[ks] = *reinterpret_cast<const bh8*>(wlp + ks * 32);
                    }
                } else {
                    const float* Wm = (pidx == 0) ? At_w : (pidx == 1) ? Ac_w : Bc_w;
                    const float* bp = Wm + (size_t)gcol * EMB + (g << 3);
                    #pragma unroll
                    for (int ks = 0; ks < 4; ++ks) split8(bp + ks * 32, wh[ks], wl[ks]);
                }
                const float* Wb = (pidx == 0) ? At_b : (pidx == 1) ? Ac_b : Bc_b;
                bias = Wb[gcol];
            }
            const int nrows = (pidx == 0) ? NT : NC;
            const float* Xb = (pidx == 0) ? gq : (pidx == 1) ? gk : gv;
            int ar = mt2 * 16 + l15; if (ar > nrows - 1) ar = nrows - 1;
            const float* ap = Xb + (size_t)b * nrows * EMB + (size_t)ar * EMB + (g << 3);
            f4acc acc2 = {bias, bias, bias, bias};
            #pragma unroll
            for (int ks = 0; ks < 4; ++ks) {
                bh8 xh, xl;
                split8(ap + ks * 32, xh, xl);
                acc2 = mfma_bf16(xh, wh[ks], acc2);
                acc2 = mfma_bf16(xl, wh[ks], acc2);
                acc2 = mfma_bf16(xh, wl[ks], acc2);
            }
            #pragma unroll
            for (int r = 0; r < 4; ++r) {
                const int row = mt2 * 16 + (g << 2) + r;
                if (row < nrows) {
                    const unsigned short hv = bf16rne(acc2[r]);
                    if (pidx == 0)      sQ[row * 40 + col] = hv;
                    else if (pidx == 1) sK[row * 40 + col] = hv;
                    else                sVT[col * 232 + row] = hv;
                }
            }
        }
    }
    __syncthreads();

    if (t < 250) {
        unsigned short* rowp = (t < 200) ? (sK + t * 40) : (sQ + (t - 200) * 40);
        unsigned int* w32 = reinterpret_cast<unsigned int*>(rowp);
        unsigned int w[16];
        #pragma unroll
        for (int i = 0; i < 16; ++i) w[i] = w32[i];
        float s = 0.f;
        #pragma unroll
        for (int i = 0; i < 16; ++i) {
            const float a = __uint_as_float(w[i] << 16);
            const float c = __uint_as_float(w[i] & 0xFFFF0000u);
            s += a * a + c * c;
        }
        const float rs = rsqrtf(fmaxf(s, 1e-12f));
        #pragma unroll
        for (int i = 0; i < 16; ++i) {
            const float a = __uint_as_float(w[i] << 16) * rs;
            const float c = __uint_as_float(w[i] & 0xFFFF0000u) * rs;
            unsigned int pw;
            asm("v_cvt_pk_bf16_f32 %0, %1, %2" : "=v"(pw) : "v"(a), "v"(c));
            w32[i] = pw;
        }
    }
    __syncthreads();

    const int mt = wave & 3, hf = wave >> 2;
    const int m0 = mt << 4;
    const int row64 = m0 + (g << 2);
    int arow = m0 + l15; if (arow > NT - 1) arow = NT - 1;
    const bh8 aq = *reinterpret_cast<const bh8*>(sQ + arow * 40 + (g << 3));

    f4acc acc[7];
    #pragma unroll
    for (int i = 0; i < 7; ++i) {
        const int nt = hf * 7 + i;
        if (nt < 13) {
            const int col = (nt << 4) + l15;
            const int bc = (col < NC) ? col : (NC - 1);
            const bh8 bk = *reinterpret_cast<const bh8*>(sK + bc * 40 + (g << 3));
            f4acc c = {0.f, 0.f, 0.f, 0.f};
            c = mfma_bf16(aq, bk, c);
            const float pbl = spb[bc];
            #pragma unroll
            for (int r = 0; r < 4; ++r)
                acc[i][r] = (col < NC) ? fmaf(c[r], LOG2E, pbl) : -1e30f;
        }
    }
    __syncthreads();

    {
        unsigned int* p32 = reinterpret_cast<unsigned int*>(sP);
        for (int tt = t; tt < 700; tt += THREADS) {
            const int row = tt / 14, i = tt - row * 14;
            p32[row * 116 + 100 + i] = 0u;
        }
    }
    {
        float sl[4] = {0.f, 0.f, 0.f, 0.f};
        #pragma unroll
        for (int i = 0; i < 7; ++i) {
            if (hf * 7 + i < 13) {
                #pragma unroll
                for (int r = 0; r < 4; ++r) {
                    const float e = __builtin_exp2f(acc[i][r]);
                    acc[i][r] = e;
                    sl[r] += e;
                }
            }
        }
        #pragma unroll
        for (int r = 0; r < 4; ++r) {
            sl[r] += __shfl_xor(sl[r], 1);
            sl[r] += __shfl_xor(sl[r], 2);
            sl[r] += __shfl_xor(sl[r], 4);
            sl[r] += __shfl_xor(sl[r], 8);
        }
        if (l15 == 0) {
            #pragma unroll
            for (int r = 0; r < 4; ++r) sSm[hf * 64 + row64 + r] = sl[r];
        }
    }
    __syncthreads();

    {
        float inv[4];
        #pragma unroll
        for (int r = 0; r < 4; ++r)
            inv[r] = 1.0f / (sSm[row64 + r] + sSm[64 + row64 + r]);
        float* attb = att + (size_t)(b * NH + h) * NT * NC;
        #pragma unroll
        for (int i = 0; i < 7; ++i) {
            const int nt = hf * 7 + i;
            if (nt < 13) {
                const int col = (nt << 4) + l15;
                if (col < NC) {
                    #pragma unroll
                    for (int r = 0; r < 4; ++r) {
                        const int row = row64 + r;
                        if (row < NT) {
                            const float v = acc[i][r] * inv[r];
                            attb[row * NC + col] = v;
                            sP[row * 232 + col] = bf16rne(v);
                        }
                    }
                }
            }
        }
    }
    __syncthreads();

    {
        const int pnt = wave >> 2;
        const unsigned short* pA = sP + arow * 232;
        const unsigned short* pB = sVT + (size_t)((pnt << 4) + l15) * 232;
        f4acc o = {0.f, 0.f, 0.f, 0.f};
        #pragma unroll
        for (int ks = 0; ks < 7; ++ks) {
            const bh8 a = *reinterpret_cast<const bh8*>(pA + ks * 32 + (g << 3));
            const bh8 v = *reinterpret_cast<const bh8*>(pB + ks * 32 + (g << 3));
            o = mfma_bf16(a, v, o);
        }
        if (WSP) {
            float* wsb = cat + (size_t)b * (NT * NH * DH) + h * DH;
            #pragma unroll
            for (int r = 0; r < 4; ++r) {
                const int row = row64 + r;
                if (row < NT) wsb[(size_t)row * (NH * DH) + (pnt << 4) + l15] = o[r];
            }
        } else {
            __syncthreads();
            float* sOH = reinterpret_cast<float*>(smem);
            #pragma unroll
            for (int r = 0; r < 4; ++r) {
                const int row = row64 + r;
                if (row < NT) sOH[row * DH + (pnt << 4) + l15] = o[r];
            }
            __syncthreads();
            for (int oo = t; oo < NT * EMB; oo += THREADS) {
                const int r = oo >> 7, e = oo & 127;
                float s = (h == 0) ? R_b[e] : 0.f;
                const float* rw = R_w + (size_t)e * (NH * DH) + h * DH;
                const float* oh = sOH + r * DH;
                #pragma unroll
                for (int c = 0; c < DH; ++c) s += oh[c] * rw[c];
                atomicAdd(&out[((size_t)b * NT + r) * EMB + e], s);
            }
        }
    }
}

// rproj4: MFMA GEMM. out[51200x128] = cat[51200x256] @ R_w[128x256]^T + R_b.
__global__ __launch_bounds__(256, 4) void rproj4(
    const float* __restrict__ cat, const unsigned short* __restrict__ rhi,
    const float* __restrict__ R_b, float* __restrict__ out)
{
    const int t = threadIdx.x;
    const int lane = t & 63, wave = t >> 6;
    const int l15 = lane & 15, g = lane >> 4;
    const int m0 = blockIdx.x * 64 + wave * 16;
    const float* ap = cat + (size_t)(m0 + l15) * 256 + (g << 3);
    const unsigned short* rlo = rhi + (WS_R_LO - WS_R_HI);

    f4acc acc[8];
    #pragma unroll
    for (int nt = 0; nt < 8; ++nt) {
        const float rb = R_b[nt * 16 + l15];
        acc[nt][0] = rb; acc[nt][1] = rb; acc[nt][2] = rb; acc[nt][3] = rb;
    }
    #pragma unroll
    for (int ks = 0; ks < 8; ++ks) {
        bh8 ah, al;
        split8(ap + ks * 32, ah, al);
        #pragma unroll
        for (int nt = 0; nt < 8; ++nt) {
            const size_t o = (size_t)(nt * 16 + l15) * 256 + ks * 32 + (g << 3);
            const bh8 bh_ = *reinterpret_cast<const bh8*>(rhi + o);
            const bh8 bl_ = *reinterpret_cast<const bh8*>(rlo + o);
            acc[nt] = mfma_bf16(ah, bh_, acc[nt]);
            acc[nt] = mfma_bf16(al, bh_, acc[nt]);
            acc[nt] = mfma_bf16(ah, bl_, acc[nt]);
        }
    }
    const int row = m0 + (g << 2);
    #pragma unroll
    for (int nt = 0; nt < 8; ++nt) {
        #pragma unroll
        for (int r = 0; r < 4; ++r)
            out[(size_t)(row + r) * EMB + nt * 16 + l15] = acc[nt][r];
    }
}

extern "C" void kernel_launch(void* const* d_in, const int* in_sizes, int n_in,
                              void* d_out, int out_size, void* d_ws, size_t ws_size,
                              hipStream_t stream)
{
    const float* gq   = (const float*)d_in[0];
    const float* gk   = (const float*)d_in[1];
    const float* gv   = (const float*)d_in[2];
    const float* At_w = (const float*)d_in[3];
    const float* At_b = (const float*)d_in[4];
    const float* Ac_w = (const float*)d_in[5];
    const float* Ac_b = (const float*)d_in[6];
    const float* Bc_w = (const float*)d_in[7];
    const float* Bc_b = (const float*)d_in[8];
    const float* pb   = (const float*)d_in[9];
    const float* R_w  = (const float*)d_in[10];
    const float* R_b  = (const float*)d_in[11];

    const int nbat = in_sizes[0] / (NT * EMB);   // 1024
    float* out = (float*)d_out;
    float* att = out + (size_t)nbat * NT * EMB;

    const size_t qB   = (size_t)nbat * NT * 256 * 2;
    const size_t kB   = (size_t)nbat * NC * 256 * 2;
    const size_t catB = (size_t)nbat * NT * NH * DH * sizeof(float);
    const size_t need3 = WS_PLANES_B + qB + 2 * kB + catB;   // ~290 MB
    const size_t need2 = WS_PLANES_B + catB;                 // ~53 MB
    const int nwg = nbat * NH;

    if (ws_size >= need3) {
        unsigned short* wsp = (unsigned short*)d_ws;
        unsigned short* qh = (unsigned short*)((char*)d_ws + WS_PLANES_B);
        unsigned short* kh = (unsigned short*)((char*)d_ws + WS_PLANES_B + qB);
        unsigned short* vh = (unsigned short*)((char*)d_ws + WS_PLANES_B + qB + kB);
        float* cat = (float*)((char*)d_ws + WS_PLANES_B + qB + 2 * kB);
        wprep<<<56, 512, 0, stream>>>(At_w, Ac_w, Bc_w, R_w, wsp);
        projn<<<nbat * 15, 512, 0, stream>>>(gq, gk, gv, At_b, Ac_b, Bc_b,
                                             wsp, qh, kh, vh);
        attn2<<<nwg, THREADS, 0, stream>>>(qh, kh, vh, pb, att, cat, nbat);
        rproj4<<<(nbat * NT) / 64, 256, 0, stream>>>(cat, wsp + WS_R_HI, R_b, out);
    } else if (ws_size >= need2) {
        unsigned short* wsp = (unsigned short*)d_ws;
        float* cat = (float*)((char*)d_ws + WS_PLANES_B);
        wprep<<<56, 512, 0, stream>>>(At_w, Ac_w, Bc_w, R_w, wsp);
        attn_mfma<1><<<nwg, THREADS, 0, stream>>>(
            gq, gk, gv, At_w, At_b, Ac_w, Ac_b, Bc_w, Bc_b, pb, R_w, R_b,
            out, att, cat, wsp, nbat);
        rproj4<<<(nbat * NT) / 64, 256, 0, stream>>>(cat, wsp + WS_R_HI, R_b, out);
    } else {
        hipMemsetAsync(d_out, 0, (size_t)nbat * NT * EMB * sizeof(float), stream);
        attn_mfma<0><<<nwg, THREADS, 0, stream>>>(
            gq, gk, gv, At_w, At_b, Ac_w, Ac_b, Bc_w, Bc_b, pb, R_w, R_b,
            out, att, nullptr, nullptr, nbat);
    }
}

// Round 12
// 355.012 us; speedup vs baseline: 2.1143x; 1.0398x over previous
//
#include <hip/hip_runtime.h>

// ---------------------------------------------------------------------------
// Cosine-similarity MHA, round 12:
//  projn v4: persistent 10-tile pipelined blocks (grid = 3*nbat), double-
//    buffered sX (1 barrier/tile), wave-private sO flush (0 barriers),
//    W frags loaded once per type from swizzled plane.
//  attn2 / rproj4 / wprep: unchanged from round 11.
// ---------------------------------------------------------------------------

#define NT 50
#define NC 200
#define EMB 128
#define DH 32
#define NH 8
#define THREADS 512
#define LOG2E 1.44269504088896340736f

#define WS_PROJ_LO 98304u       // short offset of proj lo plane
#define WS_R_HI    196608u      // short offset of R hi plane
#define WS_R_LO    229376u      // short offset of R lo plane
#define WS_PSW     262144u      // short offset of swizzled proj hi plane
#define WS_PLANES_B 720896u     // bytes: end of weight planes (incl swizzled)

typedef __attribute__((ext_vector_type(4))) float f4acc;
typedef __attribute__((ext_vector_type(8))) short bh8;

__device__ __forceinline__ f4acc mfma_bf16(bh8 a, bh8 b, f4acc c) {
    return __builtin_amdgcn_mfma_f32_16x16x32_bf16(a, b, c, 0, 0, 0);
}

__device__ __forceinline__ unsigned short bf16rne(float x) {
    unsigned int u = __float_as_uint(x);
    u += 0x7FFFu + ((u >> 16) & 1u);
    return (unsigned short)(u >> 16);
}

// 8 f32 -> bf16 RNE (packed); pair order identical for A and B operands.
__device__ __forceinline__ bh8 cvt8(const float* __restrict__ p) {
    float4 x0 = *reinterpret_cast<const float4*>(p);
    float4 x1 = *reinterpret_cast<const float4*>(p + 4);
    float xs[8] = {x0.x, x0.y, x0.z, x0.w, x1.x, x1.y, x1.z, x1.w};
    union { unsigned int w[4]; bh8 v; } H;
    #pragma unroll
    for (int i = 0; i < 4; ++i)
        asm("v_cvt_pk_bf16_f32 %0, %1, %2"
            : "=v"(H.w[i]) : "v"(xs[2 * i]), "v"(xs[2 * i + 1]));
    return H.v;
}

__device__ __forceinline__ void split8(const float* __restrict__ p, bh8& hi, bh8& lo) {
    float4 x0 = *reinterpret_cast<const float4*>(p);
    float4 x1 = *reinterpret_cast<const float4*>(p + 4);
    float xs[8] = {x0.x, x0.y, x0.z, x0.w, x1.x, x1.y, x1.z, x1.w};
    union { unsigned int w[4]; bh8 v; } H, L;
    #pragma unroll
    for (int i = 0; i < 4; ++i) {
        const float a = xs[2 * i], b = xs[2 * i + 1];
        unsigned int hw, lw;
        asm("v_cvt_pk_bf16_f32 %0, %1, %2" : "=v"(hw) : "v"(a), "v"(b));
        const float ha = __uint_as_float(hw << 16);
        const float hb = __uint_as_float(hw & 0xFFFF0000u);
        const float la = a - ha, lb = b - hb;
        asm("v_cvt_pk_bf16_f32 %0, %1, %2" : "=v"(lw) : "v"(la), "v"(lb));
        H.w[i] = hw; L.w[i] = lw;
    }
    hi = H.v; lo = L.v;
}

// ---- wprep: linear hi/lo planes + R planes + fragment-major swizzled plane --
__global__ __launch_bounds__(512) void wprep(
    const float* __restrict__ At_w, const float* __restrict__ Ac_w,
    const float* __restrict__ Bc_w, const float* __restrict__ R_w,
    unsigned short* __restrict__ ws)
{
    const int u = blockIdx.x * 512 + threadIdx.x;     // 28672 units of 8 elems
    bh8 h8, l8;
    if (u < 12288) {                                  // proj: [3][256][128]
        const int p = u >> 12, rem = u & 4095;
        const int col = rem >> 4, e0 = (rem & 15) << 3;
        const float* W = (p == 0) ? At_w : (p == 1) ? Ac_w : Bc_w;
        split8(W + (size_t)col * 128 + e0, h8, l8);
        const size_t o = ((size_t)p * 256 + col) * 128 + e0;
        *reinterpret_cast<bh8*>(ws + o) = h8;
        *reinterpret_cast<bh8*>(ws + WS_PROJ_LO + o) = l8;
    } else if (u < 16384) {                           // R: [128][256]
        const int u2 = u - 12288;
        const int e = u2 >> 5, k0 = (u2 & 31) << 3;
        split8(R_w + (size_t)e * 256 + k0, h8, l8);
        const size_t o = (size_t)e * 256 + k0;
        *reinterpret_cast<bh8*>(ws + WS_R_HI + o) = h8;
        *reinterpret_cast<bh8*>(ws + WS_R_LO + o) = l8;
    } else {                                          // swizzled proj hi
        const int u2 = u - 16384;                     // 12288 units
        const int lane = u2 & 63;
        const int ks = (u2 >> 6) & 3;
        const int colgrp = (u2 >> 8) & 1;
        const int head = (u2 >> 9) & 7;
        const int ty = u2 >> 12;
        const float* W = (ty == 0) ? At_w : (ty == 1) ? Ac_w : Bc_w;
        const int col = head * 32 + colgrp * 16 + (lane & 15);
        const int g = lane >> 4;
        *reinterpret_cast<bh8*>(ws + WS_PSW + (size_t)u2 * 8) =
            cvt8(W + (size_t)col * 128 + ks * 32 + g * 8);
    }
}

__device__ __forceinline__ void projn_wfrag(
    const unsigned short* __restrict__ wsp, int ty, int head, int lane,
    bh8* bf0, bh8* bf1)
{
    const unsigned short* base = wsp + WS_PSW + ((size_t)(ty * 8 + head) << 12)
                               + (size_t)lane * 8;
    #pragma unroll
    for (int ks = 0; ks < 4; ++ks) {
        bf0[ks] = *reinterpret_cast<const bh8*>(base + (ks << 9));
        bf1[ks] = *reinterpret_cast<const bh8*>(base + 2048 + (ks << 9));
    }
}

__device__ __forceinline__ void tinfo(int r, int& ty, int& mt, int& nrows) {
    ty = (r < 4) ? 0 : (r < 17) ? 1 : 2;
    mt = r - ((ty == 0) ? 0 : (ty == 1) ? 4 : 17);
    nrows = (ty == 0) ? NT : NC;
}

// ---- projn v4: persistent 10-tile pipelined block ----
// block = (batch, third): tiles r = third*10 .. third*10+9.
// Per tile: prefetch X[i+1]->regs, compute from sX[i&1], wave-private pack+
// flush via sO (no barrier), write X[i+1]->sX[(i+1)&1], ONE barrier.
__global__ __launch_bounds__(512, 6) void projn(
    const float* __restrict__ gq, const float* __restrict__ gk,
    const float* __restrict__ gv,
    const float* __restrict__ At_b, const float* __restrict__ Ac_b,
    const float* __restrict__ Bc_b,
    const unsigned short* __restrict__ wsp,
    unsigned short* __restrict__ qh, unsigned short* __restrict__ kh,
    unsigned short* __restrict__ vh)
{
    __shared__ __align__(16) float sX[2][16][132];
    __shared__ __align__(16) unsigned short sO[16 * 264];   // pad: 264 shorts

    const int blk = blockIdx.x;
    const int b = blk / 3, third = blk - b * 3;
    const int t = threadIdx.x;
    const int lane = t & 63, head = t >> 6, l15 = lane & 15, g = lane >> 4;
    const int c0i = head * 32 + l15, c1i = c0i + 16;
    const int srow = t >> 5, scol = (t & 31) * 4;     // stage coords
    const int fr = lane >> 2, fc = lane & 3;          // flush coords

    const float* Xb[3] = {gq + (size_t)b * NT * EMB,
                          gk + (size_t)b * NC * EMB,
                          gv + (size_t)b * NC * EMB};
    unsigned short* Ob[3] = {qh + (size_t)b * (NT * 256),
                             kh + (size_t)b * (NC * 256),
                             vh + (size_t)b * (NC * 256)};
    const float* Bb[3] = {At_b, Ac_b, Bc_b};

    const int r0 = third * 10;
    int ty, mt, nrows;
    tinfo(r0, ty, mt, nrows);

    // prologue: stage tile r0 -> sX[0]; W frags + bias for its type
    {
        int row = mt * 16 + srow; if (row > nrows - 1) row = nrows - 1;
        *reinterpret_cast<float4*>(&sX[0][srow][scol]) =
            *reinterpret_cast<const float4*>(Xb[ty] + (size_t)row * EMB + scol);
    }
    bh8 bf0[4], bf1[4];
    projn_wfrag(wsp, ty, head, lane, bf0, bf1);
    float bias0 = Bb[ty][c0i], bias1 = Bb[ty][c1i];
    __syncthreads();

    for (int i = 0; i < 10; ++i) {
        const int cur = i & 1;
        const int cty = ty, cmt = mt, cnrows = nrows;

        // prefetch next tile X into registers
        float4 xreg;
        const bool have_next = (i + 1 < 10);
        int nty = ty, nmt = mt, nnrows = nrows;
        if (have_next) {
            tinfo(r0 + i + 1, nty, nmt, nnrows);
            int row = nmt * 16 + srow; if (row > nnrows - 1) row = nnrows - 1;
            xreg = *reinterpret_cast<const float4*>(
                Xb[nty] + (size_t)row * EMB + scol);
        }

        // compute current tile
        f4acc a0 = {bias0, bias0, bias0, bias0};
        f4acc a1 = {bias1, bias1, bias1, bias1};
        #pragma unroll
        for (int ks = 0; ks < 4; ++ks) {
            const bh8 xv = cvt8(&sX[cur][l15][ks * 32 + (g << 3)]);
            a0 = mfma_bf16(xv, bf0[ks], a0);
            a1 = mfma_bf16(xv, bf1[ks], a1);
        }
        if (cty < 2) {                                 // normalize q/k rows
            float s[4];
            #pragma unroll
            for (int rr = 0; rr < 4; ++rr) s[rr] = a0[rr] * a0[rr] + a1[rr] * a1[rr];
            #pragma unroll
            for (int rr = 0; rr < 4; ++rr) {
                s[rr] += __shfl_xor(s[rr], 1);
                s[rr] += __shfl_xor(s[rr], 2);
                s[rr] += __shfl_xor(s[rr], 4);
                s[rr] += __shfl_xor(s[rr], 8);
            }
            #pragma unroll
            for (int rr = 0; rr < 4; ++rr) {
                const float rs = rsqrtf(fmaxf(s[rr], 1e-12f));
                a0[rr] *= rs; a1[rr] *= rs;
            }
        }
        // pack into sO (wave-private columns head*32..head*32+31)
        #pragma unroll
        for (int rr = 0; rr < 4; ++rr) {
            const int row = (g << 2) + rr;
            sO[row * 264 + c0i] = bf16rne(a0[rr]);
            sO[row * 264 + c1i] = bf16rne(a1[rr]);
        }
        asm volatile("" ::: "memory");                 // keep pack before flush
        // wave-local flush (same wave wrote these 32 cols; DS in-order)
        {
            const int grow = cmt * 16 + fr;
            if (grow < cnrows)
                *reinterpret_cast<bh8*>(
                    Ob[cty] + (size_t)grow * 256 + head * 32 + fc * 8) =
                    *reinterpret_cast<const bh8*>(&sO[fr * 264 + head * 32 + fc * 8]);
        }
        // stage next tile into the other buffer; reload W on type change
        if (have_next) {
            *reinterpret_cast<float4*>(&sX[cur ^ 1][srow][scol]) = xreg;
            if (nty != cty) {
                projn_wfrag(wsp, nty, head, lane, bf0, bf1);
                bias0 = Bb[nty][c0i]; bias1 = Bb[nty][c1i];
            }
            ty = nty; mt = nmt; nrows = nnrows;
        }
        __syncthreads();
    }
}

// ---- attn2: scores + softmax + att + PV + cat, from prestaged bf16 ----
__global__ __launch_bounds__(512, 6) void attn2(
    const unsigned short* __restrict__ qh, const unsigned short* __restrict__ kh,
    const unsigned short* __restrict__ vh, const float* __restrict__ pos_bias,
    float* __restrict__ att, float* __restrict__ cat, int nbat)
{
    const int t = threadIdx.x;
    const int p = blockIdx.x;
    const int chunk = (nbat * NH) >> 3;
    const int lj = (p & 7) * chunk + (p >> 3);
    const int b = lj >> 3, h = lj & 7;
    const int lane = t & 63, wave = t >> 6, l15 = lane & 15, g = lane >> 4;

    __shared__ __align__(16) unsigned char smem[39872];
    unsigned short* sVT = reinterpret_cast<unsigned short*>(smem);
    unsigned short* sK  = reinterpret_cast<unsigned short*>(smem + 14848);
    unsigned short* sQ  = reinterpret_cast<unsigned short*>(smem + 30848);
    unsigned short* sP  = reinterpret_cast<unsigned short*>(smem + 14848);
    float* spb = reinterpret_cast<float*>(smem + 38048);
    float* sSm = reinterpret_cast<float*>(smem + 39360);

    if (t < 448) {
        unsigned int* v32 = reinterpret_cast<unsigned int*>(sVT);
        const int col = t / 14, i = t - col * 14;
        v32[col * 116 + 100 + i] = 0u;
    }
    if (t < NC) spb[t] = pos_bias[t] * LOG2E;
    if (t < 200) {
        const int row = t >> 2, q = t & 3;
        *reinterpret_cast<bh8*>(sQ + row * 40 + q * 8) =
            *reinterpret_cast<const bh8*>(qh + (size_t)b * (NT * 256) + row * 256 + h * 32 + q * 8);
    }
    for (int u = t; u < 800; u += THREADS) {
        const int row = u >> 2, q = u & 3;
        *reinterpret_cast<bh8*>(sK + row * 40 + q * 8) =
            *reinterpret_cast<const bh8*>(kh + (size_t)b * (NC * 256) + row * 256 + h * 32 + q * 8);
    }
    for (int u = t; u < 800; u += THREADS) {
        const int row = u >> 2, q = u & 3;
        const bh8 vv = *reinterpret_cast<const bh8*>(
            vh + (size_t)b * (NC * 256) + row * 256 + h * 32 + q * 8);
        #pragma unroll
        for (int e = 0; e < 8; ++e)
            sVT[(q * 8 + e) * 232 + row] = (unsigned short)vv[e];
    }
    __syncthreads();

    const int mt = wave & 3, hf = wave >> 2;
    const int m0 = mt << 4;
    const int row64 = m0 + (g << 2);
    int arow = m0 + l15; if (arow > NT - 1) arow = NT - 1;
    const bh8 aq = *reinterpret_cast<const bh8*>(sQ + arow * 40 + (g << 3));

    f4acc acc[7];
    #pragma unroll
    for (int i = 0; i < 7; ++i) {
        const int nt = hf * 7 + i;
        if (nt < 13) {
            const int col = (nt << 4) + l15;
            const int bc = (col < NC) ? col : (NC - 1);
            const bh8 bk = *reinterpret_cast<const bh8*>(sK + bc * 40 + (g << 3));
            f4acc c = {0.f, 0.f, 0.f, 0.f};
            c = mfma_bf16(aq, bk, c);
            const float pbl = spb[bc];
            #pragma unroll
            for (int r = 0; r < 4; ++r)
                acc[i][r] = (col < NC) ? fmaf(c[r], LOG2E, pbl) : -1e30f;
        }
    }
    __syncthreads();

    {
        unsigned int* p32 = reinterpret_cast<unsigned int*>(sP);
        for (int tt = t; tt < 700; tt += THREADS) {
            const int row = tt / 14, i = tt - row * 14;
            p32[row * 116 + 100 + i] = 0u;
        }
    }
    {
        float sl[4] = {0.f, 0.f, 0.f, 0.f};
        #pragma unroll
        for (int i = 0; i < 7; ++i) {
            if (hf * 7 + i < 13) {
                #pragma unroll
                for (int r = 0; r < 4; ++r) {
                    const float e = __builtin_exp2f(acc[i][r]);
                    acc[i][r] = e;
                    sl[r] += e;
                }
            }
        }
        #pragma unroll
        for (int r = 0; r < 4; ++r) {
            sl[r] += __shfl_xor(sl[r], 1);
            sl[r] += __shfl_xor(sl[r], 2);
            sl[r] += __shfl_xor(sl[r], 4);
            sl[r] += __shfl_xor(sl[r], 8);
        }
        if (l15 == 0) {
            #pragma unroll
            for (int r = 0; r < 4; ++r) sSm[hf * 64 + row64 + r] = sl[r];
        }
    }
    __syncthreads();

    {
        float inv[4];
        #pragma unroll
        for (int r = 0; r < 4; ++r)
            inv[r] = 1.0f / (sSm[row64 + r] + sSm[64 + row64 + r]);
        float* attb = att + (size_t)(b * NH + h) * NT * NC;
        #pragma unroll
        for (int i = 0; i < 7; ++i) {
            const int nt = hf * 7 + i;
            if (nt < 13) {
                const int col = (nt << 4) + l15;
                if (col < NC) {
                    #pragma unroll
                    for (int r = 0; r < 4; ++r) {
                        const int row = row64 + r;
                        if (row < NT) {
                            const float v = acc[i][r] * inv[r];
                            attb[row * NC + col] = v;
                            sP[row * 232 + col] = bf16rne(v);
                        }
                    }
                }
            }
        }
    }
    __syncthreads();

    {
        const int pnt = wave >> 2;
        const unsigned short* pA = sP + arow * 232;
        const unsigned short* pB = sVT + (size_t)((pnt << 4) + l15) * 232;
        f4acc o = {0.f, 0.f, 0.f, 0.f};
        #pragma unroll
        for (int ks = 0; ks < 7; ++ks) {
            const bh8 a = *reinterpret_cast<const bh8*>(pA + ks * 32 + (g << 3));
            const bh8 v = *reinterpret_cast<const bh8*>(pB + ks * 32 + (g << 3));
            o = mfma_bf16(a, v, o);
        }
        float* wsb = cat + (size_t)b * (NT * NH * DH) + h * DH;
        #pragma unroll
        for (int r = 0; r < 4; ++r) {
            const int row = row64 + r;
            if (row < NT) wsb[(size_t)row * (NH * DH) + (pnt << 4) + l15] = o[r];
        }
    }
}

// ================= round-8 kernel retained as tier-2/3 fallback =============
template <int WSP>
__global__ __launch_bounds__(THREADS, 4) void attn_mfma(
    const float* __restrict__ gq, const float* __restrict__ gk,
    const float* __restrict__ gv,
    const float* __restrict__ At_w, const float* __restrict__ At_b,
    const float* __restrict__ Ac_w, const float* __restrict__ Ac_b,
    const float* __restrict__ Bc_w, const float* __restrict__ Bc_b,
    const float* __restrict__ pos_bias,
    const float* __restrict__ R_w, const float* __restrict__ R_b,
    float* __restrict__ out, float* __restrict__ att,
    float* __restrict__ cat, const unsigned short* __restrict__ wsp,
    int nbat)
{
    const int t = threadIdx.x;
    const int p = blockIdx.x;
    const int chunk = (nbat * NH) >> 3;
    const int lj = (p & 7) * chunk + (p >> 3);
    const int b = lj >> 3;
    const int h = lj & 7;
    const int lane = t & 63, wave = t >> 6;
    const int l15 = lane & 15, g = lane >> 4;

    __shared__ __align__(16) unsigned char smem[39872];
    unsigned short* sVT = reinterpret_cast<unsigned short*>(smem);
    unsigned short* sK  = reinterpret_cast<unsigned short*>(smem + 14848);
    unsigned short* sQ  = reinterpret_cast<unsigned short*>(smem + 30848);
    unsigned short* sP  = reinterpret_cast<unsigned short*>(smem + 14848);
    float* spb = reinterpret_cast<float*>(smem + 38048);
    float* sSm = reinterpret_cast<float*>(smem + 39360);

    if (t < 448) {
        unsigned int* v32 = reinterpret_cast<unsigned int*>(sVT);
        const int col = t / 14, i = t - col * 14;
        v32[col * 116 + 100 + i] = 0u;
    }
    if (t < NC) spb[t] = pos_bias[t] * LOG2E;

    {
        const int s0 = (wave * 60) >> 3;
        const int s1 = ((wave + 1) * 60) >> 3;
        int cp = -1, cn = -1;
        bh8 wh[4], wl[4];
        float bias = 0.f;
        for (int id = s0; id < s1; ++id) {
            int pidx, nt, mt2;
            if (id < 8)       { pidx = 0; nt = id >> 2; mt2 = id & 3; }
            else if (id < 34) { int jj = id - 8;  pidx = 1; nt = jj / 13; mt2 = jj - nt * 13; }
            else              { int jj = id - 34; pidx = 2; nt = jj / 13; mt2 = jj - nt * 13; }
            const int col = (nt << 4) + l15;
            if (pidx != cp || nt != cn) {
                cp = pidx; cn = nt;
                const int gcol = h * DH + col;
                if (WSP) {
                    const unsigned short* whp =
                        wsp + ((size_t)pidx * 256 + gcol) * 128 + (g << 3);
                    const unsigned short* wlp = whp + WS_PROJ_LO;
                    #pragma unroll
                    for (int ks = 0; ks < 4; ++ks) {
                        wh[ks] = *reinterpret_cast<const bh8*>(whp + ks * 32);
                        wl[ks] = *reinterpret_cast<const bh8*>(wlp + ks * 32);
                    }
                } else {
                    const float* Wm = (pidx == 0) ? At_w : (pidx == 1) ? Ac_w : Bc_w;
                    const float* bp = Wm + (size_t)gcol * EMB + (g << 3);
                    #pragma unroll
                    for (int ks = 0; ks < 4; ++ks) split8(bp + ks * 32, wh[ks], wl[ks]);
                }
                const float* Wb = (pidx == 0) ? At_b : (pidx == 1) ? Ac_b : Bc_b;
                bias = Wb[gcol];
            }
            const int nrows = (pidx == 0) ? NT : NC;
            const float* Xbp = (pidx == 0) ? gq : (pidx == 1) ? gk : gv;
            int ar = mt2 * 16 + l15; if (ar > nrows - 1) ar = nrows - 1;
            const float* ap = Xbp + (size_t)b * nrows * EMB + (size_t)ar * EMB + (g << 3);
            f4acc acc2 = {bias, bias, bias, bias};
            #pragma unroll
            for (int ks = 0; ks < 4; ++ks) {
                bh8 xh, xl;
                split8(ap + ks * 32, xh, xl);
                acc2 = mfma_bf16(xh, wh[ks], acc2);
                acc2 = mfma_bf16(xl, wh[ks], acc2);
                acc2 = mfma_bf16(xh, wl[ks], acc2);
            }
            #pragma unroll
            for (int r = 0; r < 4; ++r) {
                const int row = mt2 * 16 + (g << 2) + r;
                if (row < nrows) {
                    const unsigned short hv = bf16rne(acc2[r]);
                    if (pidx == 0)      sQ[row * 40 + col] = hv;
                    else if (pidx == 1) sK[row * 40 + col] = hv;
                    else                sVT[col * 232 + row] = hv;
                }
            }
        }
    }
    __syncthreads();

    if (t < 250) {
        unsigned short* rowp = (t < 200) ? (sK + t * 40) : (sQ + (t - 200) * 40);
        unsigned int* w32 = reinterpret_cast<unsigned int*>(rowp);
        unsigned int w[16];
        #pragma unroll
        for (int i = 0; i < 16; ++i) w[i] = w32[i];
        float s = 0.f;
        #pragma unroll
        for (int i = 0; i < 16; ++i) {
            const float a = __uint_as_float(w[i] << 16);
            const float c = __uint_as_float(w[i] & 0xFFFF0000u);
            s += a * a + c * c;
        }
        const float rs = rsqrtf(fmaxf(s, 1e-12f));
        #pragma unroll
        for (int i = 0; i < 16; ++i) {
            const float a = __uint_as_float(w[i] << 16) * rs;
            const float c = __uint_as_float(w[i] & 0xFFFF0000u) * rs;
            unsigned int pw;
            asm("v_cvt_pk_bf16_f32 %0, %1, %2" : "=v"(pw) : "v"(a), "v"(c));
            w32[i] = pw;
        }
    }
    __syncthreads();

    const int mt = wave & 3, hf = wave >> 2;
    const int m0 = mt << 4;
    const int row64 = m0 + (g << 2);
    int arow = m0 + l15; if (arow > NT - 1) arow = NT - 1;
    const bh8 aq = *reinterpret_cast<const bh8*>(sQ + arow * 40 + (g << 3));

    f4acc acc[7];
    #pragma unroll
    for (int i = 0; i < 7; ++i) {
        const int nt = hf * 7 + i;
        if (nt < 13) {
            const int col = (nt << 4) + l15;
            const int bc = (col < NC) ? col : (NC - 1);
            const bh8 bk = *reinterpret_cast<const bh8*>(sK + bc * 40 + (g << 3));
            f4acc c = {0.f, 0.f, 0.f, 0.f};
            c = mfma_bf16(aq, bk, c);
            const float pbl = spb[bc];
            #pragma unroll
            for (int r = 0; r < 4; ++r)
                acc[i][r] = (col < NC) ? fmaf(c[r], LOG2E, pbl) : -1e30f;
        }
    }
    __syncthreads();

    {
        unsigned int* p32 = reinterpret_cast<unsigned int*>(sP);
        for (int tt = t; tt < 700; tt += THREADS) {
            const int row = tt / 14, i = tt - row * 14;
            p32[row * 116 + 100 + i] = 0u;
        }
    }
    {
        float sl[4] = {0.f, 0.f, 0.f, 0.f};
        #pragma unroll
        for (int i = 0; i < 7; ++i) {
            if (hf * 7 + i < 13) {
                #pragma unroll
                for (int r = 0; r < 4; ++r) {
                    const float e = __builtin_exp2f(acc[i][r]);
                    acc[i][r] = e;
                    sl[r] += e;
                }
            }
        }
        #pragma unroll
        for (int r = 0; r < 4; ++r) {
            sl[r] += __shfl_xor(sl[r], 1);
            sl[r] += __shfl_xor(sl[r], 2);
            sl[r] += __shfl_xor(sl[r], 4);
            sl[r] += __shfl_xor(sl[r], 8);
        }
        if (l15 == 0) {
            #pragma unroll
            for (int r = 0; r < 4; ++r) sSm[hf * 64 + row64 + r] = sl[r];
        }
    }
    __syncthreads();

    {
        float inv[4];
        #pragma unroll
        for (int r = 0; r < 4; ++r)
            inv[r] = 1.0f / (sSm[row64 + r] + sSm[64 + row64 + r]);
        float* attb = att + (size_t)(b * NH + h) * NT * NC;
        #pragma unroll
        for (int i = 0; i < 7; ++i) {
            const int nt = hf * 7 + i;
            if (nt < 13) {
                const int col = (nt << 4) + l15;
                if (col < NC) {
                    #pragma unroll
                    for (int r = 0; r < 4; ++r) {
                        const int row = row64 + r;
                        if (row < NT) {
                            const float v = acc[i][r] * inv[r];
                            attb[row * NC + col] = v;
                            sP[row * 232 + col] = bf16rne(v);
                        }
                    }
                }
            }
        }
    }
    __syncthreads();

    {
        const int pnt = wave >> 2;
        const unsigned short* pA = sP + arow * 232;
        const unsigned short* pB = sVT + (size_t)((pnt << 4) + l15) * 232;
        f4acc o = {0.f, 0.f, 0.f, 0.f};
        #pragma unroll
        for (int ks = 0; ks < 7; ++ks) {
            const bh8 a = *reinterpret_cast<const bh8*>(pA + ks * 32 + (g << 3));
            const bh8 v = *reinterpret_cast<const bh8*>(pB + ks * 32 + (g << 3));
            o = mfma_bf16(a, v, o);
        }
        if (WSP) {
            float* wsb = cat + (size_t)b * (NT * NH * DH) + h * DH;
            #pragma unroll
            for (int r = 0; r < 4; ++r) {
                const int row = row64 + r;
                if (row < NT) wsb[(size_t)row * (NH * DH) + (pnt << 4) + l15] = o[r];
            }
        } else {
            __syncthreads();
            float* sOH = reinterpret_cast<float*>(smem);
            #pragma unroll
            for (int r = 0; r < 4; ++r) {
                const int row = row64 + r;
                if (row < NT) sOH[row * DH + (pnt << 4) + l15] = o[r];
            }
            __syncthreads();
            for (int oo = t; oo < NT * EMB; oo += THREADS) {
                const int r = oo >> 7, e = oo & 127;
                float s = (h == 0) ? R_b[e] : 0.f;
                const float* rw = R_w + (size_t)e * (NH * DH) + h * DH;
                const float* oh = sOH + r * DH;
                #pragma unroll
                for (int c = 0; c < DH; ++c) s += oh[c] * rw[c];
                atomicAdd(&out[((size_t)b * NT + r) * EMB + e], s);
            }
        }
    }
}

// rproj4: MFMA GEMM. out[51200x128] = cat[51200x256] @ R_w[128x256]^T + R_b.
__global__ __launch_bounds__(256, 4) void rproj4(
    const float* __restrict__ cat, const unsigned short* __restrict__ rhi,
    const float* __restrict__ R_b, float* __restrict__ out)
{
    const int t = threadIdx.x;
    const int lane = t & 63, wave = t >> 6;
    const int l15 = lane & 15, g = lane >> 4;
    const int m0 = blockIdx.x * 64 + wave * 16;
    const float* ap = cat + (size_t)(m0 + l15) * 256 + (g << 3);
    const unsigned short* rlo = rhi + (WS_R_LO - WS_R_HI);

    f4acc acc[8];
    #pragma unroll
    for (int nt = 0; nt < 8; ++nt) {
        const float rb = R_b[nt * 16 + l15];
        acc[nt][0] = rb; acc[nt][1] = rb; acc[nt][2] = rb; acc[nt][3] = rb;
    }
    #pragma unroll
    for (int ks = 0; ks < 8; ++ks) {
        bh8 ah, al;
        split8(ap + ks * 32, ah, al);
        #pragma unroll
        for (int nt = 0; nt < 8; ++nt) {
            const size_t o = (size_t)(nt * 16 + l15) * 256 + ks * 32 + (g << 3);
            const bh8 bh_ = *reinterpret_cast<const bh8*>(rhi + o);
            const bh8 bl_ = *reinterpret_cast<const bh8*>(rlo + o);
            acc[nt] = mfma_bf16(ah, bh_, acc[nt]);
            acc[nt] = mfma_bf16(al, bh_, acc[nt]);
            acc[nt] = mfma_bf16(ah, bl_, acc[nt]);
        }
    }
    const int row = m0 + (g << 2);
    #pragma unroll
    for (int nt = 0; nt < 8; ++nt) {
        #pragma unroll
        for (int r = 0; r < 4; ++r)
            out[(size_t)(row + r) * EMB + nt * 16 + l15] = acc[nt][r];
    }
}

extern "C" void kernel_launch(void* const* d_in, const int* in_sizes, int n_in,
                              void* d_out, int out_size, void* d_ws, size_t ws_size,
                              hipStream_t stream)
{
    const float* gq   = (const float*)d_in[0];
    const float* gk   = (const float*)d_in[1];
    const float* gv   = (const float*)d_in[2];
    const float* At_w = (const float*)d_in[3];
    const float* At_b = (const float*)d_in[4];
    const float* Ac_w = (const float*)d_in[5];
    const float* Ac_b = (const float*)d_in[6];
    const float* Bc_w = (const float*)d_in[7];
    const float* Bc_b = (const float*)d_in[8];
    const float* pb   = (const float*)d_in[9];
    const float* R_w  = (const float*)d_in[10];
    const float* R_b  = (const float*)d_in[11];

    const int nbat = in_sizes[0] / (NT * EMB);   // 1024
    float* out = (float*)d_out;
    float* att = out + (size_t)nbat * NT * EMB;

    const size_t qB   = (size_t)nbat * NT * 256 * 2;
    const size_t kB   = (size_t)nbat * NC * 256 * 2;
    const size_t catB = (size_t)nbat * NT * NH * DH * sizeof(float);
    const size_t need3 = WS_PLANES_B + qB + 2 * kB + catB;   // ~290 MB
    const size_t need2 = WS_PLANES_B + catB;                 // ~53 MB
    const int nwg = nbat * NH;

    if (ws_size >= need3) {
        unsigned short* wsp = (unsigned short*)d_ws;
        unsigned short* qh = (unsigned short*)((char*)d_ws + WS_PLANES_B);
        unsigned short* kh = (unsigned short*)((char*)d_ws + WS_PLANES_B + qB);
        unsigned short* vh = (unsigned short*)((char*)d_ws + WS_PLANES_B + qB + kB);
        float* cat = (float*)((char*)d_ws + WS_PLANES_B + qB + 2 * kB);
        wprep<<<56, 512, 0, stream>>>(At_w, Ac_w, Bc_w, R_w, wsp);
        projn<<<nbat * 3, 512, 0, stream>>>(gq, gk, gv, At_b, Ac_b, Bc_b,
                                            wsp, qh, kh, vh);
        attn2<<<nwg, THREADS, 0, stream>>>(qh, kh, vh, pb, att, cat, nbat);
        rproj4<<<(nbat * NT) / 64, 256, 0, stream>>>(cat, wsp + WS_R_HI, R_b, out);
    } else if (ws_size >= need2) {
        unsigned short* wsp = (unsigned short*)d_ws;
        float* cat = (float*)((char*)d_ws + WS_PLANES_B);
        wprep<<<56, 512, 0, stream>>>(At_w, Ac_w, Bc_w, R_w, wsp);
        attn_mfma<1><<<nwg, THREADS, 0, stream>>>(
            gq, gk, gv, At_w, At_b, Ac_w, Ac_b, Bc_w, Bc_b, pb, R_w, R_b,
            out, att, cat, wsp, nbat);
        rproj4<<<(nbat * NT) / 64, 256, 0, stream>>>(cat, wsp + WS_R_HI, R_b, out);
    } else {
        hipMemsetAsync(d_out, 0, (size_t)nbat * NT * EMB * sizeof(float), stream);
        attn_mfma<0><<<nwg, THREADS, 0, stream>>>(
            gq, gk, gv, At_w, At_b, Ac_w, Ac_b, Bc_w, Bc_b, pb, R_w, R_b,
            out, att, nullptr, nullptr, nbat);
    }
}